// Round 2
// baseline (277.208 us; speedup 1.0000x reference)
//
#include <hip/hip_runtime.h>
#include <hip/hip_bf16.h>

#define CI 32
#define CC 64
#define NBATCH 2
#define NPIX 9216   // 96*96
#define NSPLIT 4
#define LOG2E 1.4426950408889634f

typedef __attribute__((ext_vector_type(8))) short s16x8;
typedef __attribute__((ext_vector_type(4))) short s16x4;
typedef __attribute__((ext_vector_type(4))) float f32x4;

static __device__ __forceinline__ short f2b(float f) {
    union { float f; unsigned u; } v; v.f = f;
    return (short)((v.u + 0x7FFFu + ((v.u >> 16) & 1u)) >> 16);
}
static __device__ __forceinline__ float b2f(short s) {
    union { unsigned u; float f; } v; v.u = ((unsigned)(unsigned short)s) << 16;
    return v.f;
}

// ---------------------------------------------------------------------------
// K0: 1x1 conv projections. xA -> k,v ; xB -> q. Outputs bf16:
//   vT[b][n][c], qT[b][n][c] (pre-scaled by log2(e)), kC[b][c][n]
// ---------------------------------------------------------------------------
__global__ __launch_bounds__(256) void k_proj(
    const float* __restrict__ xA, const float* __restrict__ xB,
    const float* __restrict__ Wk, const float* __restrict__ bk,
    const float* __restrict__ Wv, const float* __restrict__ bv,
    const float* __restrict__ Wq, const float* __restrict__ bq,
    short* __restrict__ vT, short* __restrict__ qT, short* __restrict__ kC)
{
    __shared__ float sWk[CI * CC], sWv[CI * CC], sWq[CI * CC], sb[3 * CI];
    for (int i = threadIdx.x; i < CI * CC; i += 256) {
        sWk[i] = Wk[i]; sWv[i] = Wv[i]; sWq[i] = Wq[i];
    }
    if (threadIdx.x < CI) {
        sb[threadIdx.x]          = bk[threadIdx.x];
        sb[CI + threadIdx.x]     = bv[threadIdx.x];
        sb[2 * CI + threadIdx.x] = bq[threadIdx.x];
    }
    __syncthreads();

    int idx = blockIdx.x * 256 + threadIdx.x;   // 0 .. NBATCH*NPIX-1
    int b = idx / NPIX, n = idx % NPIX;

    float ak[CI], av[CI], aq[CI];
    #pragma unroll
    for (int o = 0; o < CI; o++) { ak[o] = 0.f; av[o] = 0.f; aq[o] = 0.f; }

    const float* pA = xA + (size_t)b * CC * NPIX + n;
    const float* pB = xB + (size_t)b * CC * NPIX + n;
    for (int c = 0; c < CC; c++) {
        float xa = pA[(size_t)c * NPIX];
        float xb = pB[(size_t)c * NPIX];
        #pragma unroll
        for (int o = 0; o < CI; o++) {
            ak[o] += sWk[o * CC + c] * xa;
            av[o] += sWv[o * CC + c] * xa;
            aq[o] += sWq[o * CC + c] * xb;
        }
    }

    short vv[CI], qq[CI];
    #pragma unroll
    for (int o = 0; o < CI; o++) {
        vv[o] = f2b(av[o] + sb[CI + o]);
        qq[o] = f2b((aq[o] + sb[2 * CI + o]) * LOG2E);   // fold log2(e) for exp2
        kC[((size_t)b * CI + o) * NPIX + n] = f2b(ak[o] + sb[o]);
    }
    short* dv = vT + ((size_t)b * NPIX + n) * CI;
    short* dq = qT + ((size_t)b * NPIX + n) * CI;
    #pragma unroll
    for (int o8 = 0; o8 < 4; o8++) {
        s16x8 tv, tq;
        #pragma unroll
        for (int j = 0; j < 8; j++) { tv[j] = vv[o8 * 8 + j]; tq[j] = qq[o8 * 8 + j]; }
        ((s16x8*)dv)[o8] = tv;
        ((s16x8*)dq)[o8] = tq;
    }
}

// ---------------------------------------------------------------------------
// K1: row sums of exp(S): sum_part[z][b][n] = sum over m-quarter of exp2(S')
// Each wave holds 2 fixed A-frags (32 n-rows), loops over m in 16-col tiles.
// ---------------------------------------------------------------------------
__global__ __launch_bounds__(256) void k_denom(
    const short* __restrict__ vT, const short* __restrict__ qT,
    float* __restrict__ sum_part)
{
    int w = threadIdx.x >> 6, lane = threadIdx.x & 63;
    int r = lane & 15, g = lane >> 4;
    int b = blockIdx.y;
    int n0 = blockIdx.x * 128 + w * 32;

    const short* vbase = vT + (size_t)b * NPIX * CI;
    s16x8 a0 = *(const s16x8*)(vbase + (size_t)(n0 + r) * CI + 8 * g);
    s16x8 a1 = *(const s16x8*)(vbase + (size_t)(n0 + 16 + r) * CI + 8 * g);

    f32x4 s0 = {0.f, 0.f, 0.f, 0.f}, s1 = {0.f, 0.f, 0.f, 0.f};
    f32x4 z  = {0.f, 0.f, 0.f, 0.f};
    const short* qbase = qT + (size_t)b * NPIX * CI;
    int mlo = blockIdx.z * (NPIX / NSPLIT);
    int mhi = mlo + NPIX / NSPLIT;
    for (int m0 = mlo; m0 < mhi; m0 += 16) {
        s16x8 bf = *(const s16x8*)(qbase + (size_t)(m0 + r) * CI + 8 * g);
        f32x4 d0 = __builtin_amdgcn_mfma_f32_16x16x32_bf16(a0, bf, z, 0, 0, 0);
        f32x4 d1 = __builtin_amdgcn_mfma_f32_16x16x32_bf16(a1, bf, z, 0, 0, 0);
        #pragma unroll
        for (int e = 0; e < 4; e++) {
            s0[e] += __builtin_amdgcn_exp2f(d0[e]);
            s1[e] += __builtin_amdgcn_exp2f(d1[e]);
        }
    }
    // combine the 16 lanes that share each row (xor butterfly within 16-group)
    #pragma unroll
    for (int mask = 1; mask < 16; mask <<= 1) {
        #pragma unroll
        for (int e = 0; e < 4; e++) {
            s0[e] += __shfl_xor(s0[e], mask, 64);
            s1[e] += __shfl_xor(s1[e], mask, 64);
        }
    }
    if (r == 0) {
        float* sp = sum_part + ((size_t)blockIdx.z * NBATCH + b) * NPIX;
        #pragma unroll
        for (int e = 0; e < 4; e++) {
            sp[n0 + 4 * g + e]      = s0[e];
            sp[n0 + 16 + 4 * g + e] = s1[e];
        }
    }
}

// ---------------------------------------------------------------------------
// K1b: kC[b][c][n] *= 1 / denom[b][n]   (denom = sum of NSPLIT partials)
// ---------------------------------------------------------------------------
__global__ __launch_bounds__(256) void k_scale(
    short* __restrict__ kC, const float* __restrict__ sum_part)
{
    int idx = blockIdx.x * 256 + threadIdx.x;   // 0 .. NBATCH*CI*NPIX-1
    int n = idx % NPIX;
    int b = (idx / NPIX) >> 5;
    float s = 0.f;
    #pragma unroll
    for (int zz = 0; zz < NSPLIT; zz++)
        s += sum_part[((size_t)zz * NBATCH + b) * NPIX + n];
    kC[idx] = f2b(b2f(kC[idx]) / s);
}

// ---------------------------------------------------------------------------
// K2: av_part[z][b][c][m] = sum over n-quarter of k'[c,n] * exp2(S'[n,m])
// Per wave: 16 fixed m-cols (q B-frag loaded once), loop n in 32-row chunks.
// P repacked through padded per-wave LDS tile for the PV B-frag.
// ---------------------------------------------------------------------------
__global__ __launch_bounds__(256) void k_attn(
    const short* __restrict__ vT, const short* __restrict__ qT,
    const short* __restrict__ kC, float* __restrict__ avp)
{
    __shared__ __align__(16) short plds[4][16][40];   // [wave][m-local][n-local(32)+pad]
    int w = threadIdx.x >> 6, lane = threadIdx.x & 63;
    int r = lane & 15, g = lane >> 4;
    int b = blockIdx.y;
    int m0 = blockIdx.x * 64 + w * 16;

    s16x8 bq = *(const s16x8*)(qT + ((size_t)b * NPIX + m0 + r) * CI + 8 * g);

    f32x4 acc0 = {0.f, 0.f, 0.f, 0.f}, acc1 = {0.f, 0.f, 0.f, 0.f};
    f32x4 z    = {0.f, 0.f, 0.f, 0.f};
    const short* vbase = vT + (size_t)b * NPIX * CI;
    const short* k0 = kC + ((size_t)b * CI + r) * NPIX;
    const short* k1 = kC + ((size_t)b * CI + 16 + r) * NPIX;

    int nlo = blockIdx.z * (NPIX / NSPLIT);
    int nhi = nlo + NPIX / NSPLIT;
    for (int n0 = nlo; n0 < nhi; n0 += 32) {
        s16x8 a0 = *(const s16x8*)(vbase + (size_t)(n0 + r) * CI + 8 * g);
        s16x8 a1 = *(const s16x8*)(vbase + (size_t)(n0 + 16 + r) * CI + 8 * g);
        f32x4 s0 = __builtin_amdgcn_mfma_f32_16x16x32_bf16(a0, bq, z, 0, 0, 0);
        f32x4 s1 = __builtin_amdgcn_mfma_f32_16x16x32_bf16(a1, bq, z, 0, 0, 0);

        s16x4 p0, p1;
        #pragma unroll
        for (int e = 0; e < 4; e++) {
            p0[e] = f2b(__builtin_amdgcn_exp2f(s0[e]));
            p1[e] = f2b(__builtin_amdgcn_exp2f(s1[e]));
        }
        // lane (r,g) owns P[n-local = 4g+e][m-local = r]; store n-contiguous
        *(s16x4*)&plds[w][r][4 * g]      = p0;
        *(s16x4*)&plds[w][r][16 + 4 * g] = p1;

        s16x8 pb  = *(const s16x8*)&plds[w][r][8 * g];            // B-frag P
        s16x8 ka0 = *(const s16x8*)(k0 + n0 + 8 * g);             // A-frag k rows 0-15
        s16x8 ka1 = *(const s16x8*)(k1 + n0 + 8 * g);             // A-frag k rows 16-31
        acc0 = __builtin_amdgcn_mfma_f32_16x16x32_bf16(ka0, pb, acc0, 0, 0, 0);
        acc1 = __builtin_amdgcn_mfma_f32_16x16x32_bf16(ka1, pb, acc1, 0, 0, 0);
    }

    float* dst = avp + (size_t)(blockIdx.z * NBATCH + b) * CI * NPIX;
    #pragma unroll
    for (int e = 0; e < 4; e++) {
        dst[(size_t)(4 * g + e) * NPIX + m0 + r]      = acc0[e];
        dst[(size_t)(16 + 4 * g + e) * NPIX + m0 + r] = acc1[e];
    }
}

// ---------------------------------------------------------------------------
// K3: epilogue. av = sum of partials; Wg + BN1; Wo + bo + BN2; relu(o + xB)
// ---------------------------------------------------------------------------
__global__ __launch_bounds__(256) void k_epilogue(
    const float* __restrict__ avp,
    const float* __restrict__ Wg,
    const float* __restrict__ g1g, const float* __restrict__ g1b,
    const float* __restrict__ g1m, const float* __restrict__ g1v,
    const float* __restrict__ Wo, const float* __restrict__ bo,
    const float* __restrict__ g2g, const float* __restrict__ g2b,
    const float* __restrict__ g2m, const float* __restrict__ g2v,
    const float* __restrict__ xB, float* __restrict__ out)
{
    __shared__ float sWg[CI * CI], sWo[CC * CI], s1[CI], t1[CI], s2[CC], t2[CC];
    int t = threadIdx.x;
    for (int i = t; i < CI * CI; i += 256) sWg[i] = Wg[i];
    for (int i = t; i < CC * CI; i += 256) sWo[i] = Wo[i];
    if (t < CI) {
        float s = g1g[t] * rsqrtf(g1v[t] + 1e-5f);
        s1[t] = s; t1[t] = g1b[t] - g1m[t] * s;
    } else if (t < CI + CC) {
        int j = t - CI;
        float s = g2g[j] * rsqrtf(g2v[j] + 1e-5f);
        s2[j] = s; t2[j] = g2b[j] - g2m[j] * s + bo[j] * s;  // fold conv bias
    }
    __syncthreads();

    int idx = blockIdx.x * 256 + t;
    int b = idx / NPIX, m = idx % NPIX;

    float a[CI];
    #pragma unroll
    for (int c = 0; c < CI; c++) {
        float acc = 0.f;
        #pragma unroll
        for (int zz = 0; zz < NSPLIT; zz++)
            acc += avp[(((size_t)zz * NBATCH + b) * CI + c) * NPIX + m];
        a[c] = acc;
    }
    float a2[CI];
    #pragma unroll
    for (int o = 0; o < CI; o++) {
        float acc = 0.f;
        #pragma unroll
        for (int c = 0; c < CI; c++) acc += sWg[o * CI + c] * a[c];
        a2[o] = acc * s1[o] + t1[o];
    }
    for (int j = 0; j < CC; j++) {
        float acc = 0.f;
        #pragma unroll
        for (int o = 0; o < CI; o++) acc += sWo[j * CI + o] * a2[o];
        acc = acc * s2[j] + t2[j];
        float res = acc + xB[((size_t)b * CC + j) * NPIX + m];
        out[((size_t)b * CC + j) * NPIX + m] = res > 0.f ? res : 0.f;
    }
}

// ---------------------------------------------------------------------------
extern "C" void kernel_launch(void* const* d_in, const int* in_sizes, int n_in,
                              void* d_out, int out_size, void* d_ws, size_t ws_size,
                              hipStream_t stream)
{
    const float* xA = (const float*)d_in[0];
    const float* xB = (const float*)d_in[1];
    const float* Wk = (const float*)d_in[2];
    const float* bk = (const float*)d_in[3];
    const float* Wv = (const float*)d_in[4];
    const float* bv = (const float*)d_in[5];
    const float* Wq = (const float*)d_in[6];
    const float* bq = (const float*)d_in[7];
    const float* Wg = (const float*)d_in[8];
    const float* g1g = (const float*)d_in[9];
    const float* g1b = (const float*)d_in[10];
    const float* g1m = (const float*)d_in[11];
    const float* g1v = (const float*)d_in[12];
    const float* Wo = (const float*)d_in[13];
    const float* bo = (const float*)d_in[14];
    const float* g2g = (const float*)d_in[15];
    const float* g2b = (const float*)d_in[16];
    const float* g2m = (const float*)d_in[17];
    const float* g2v = (const float*)d_in[18];
    float* out = (float*)d_out;

    char* ws = (char*)d_ws;
    const size_t SZB = (size_t)NBATCH * NPIX * CI * 2;      // 1,179,648 B
    short* vT = (short*)(ws);
    short* qT = (short*)(ws + SZB);
    short* kC = (short*)(ws + 2 * SZB);
    float* sum_part = (float*)(ws + 3 * SZB);               // NSPLIT*NBATCH*NPIX f32
    float* avp = (float*)(ws + 3 * SZB + (size_t)NSPLIT * NBATCH * NPIX * 4);

    k_proj<<<dim3(NBATCH * NPIX / 256), dim3(256), 0, stream>>>(
        xA, xB, Wk, bk, Wv, bv, Wq, bq, vT, qT, kC);
    k_denom<<<dim3(NPIX / 128, NBATCH, NSPLIT), dim3(256), 0, stream>>>(
        vT, qT, sum_part);
    k_scale<<<dim3(NBATCH * CI * NPIX / 256), dim3(256), 0, stream>>>(
        kC, sum_part);
    k_attn<<<dim3(NPIX / 64, NBATCH, NSPLIT), dim3(256), 0, stream>>>(
        vT, qT, kC, avp);
    k_epilogue<<<dim3(NBATCH * NPIX / 256), dim3(256), 0, stream>>>(
        avp, Wg, g1g, g1b, g1m, g1v, Wo, bo, g2g, g2b, g2m, g2v, xB, out);
}

// Round 3
// 154.428 us; speedup vs baseline: 1.7951x; 1.7951x over previous
//
#include <hip/hip_runtime.h>
#include <hip/hip_bf16.h>

#define CI 32
#define CC 64
#define NBATCH 2
#define NPIX 9216          // 96*96
#define NSA 8              // n-splits for k_attn
#define NSD 16             // m-splits for k_denom
#define LOG2E 1.4426950408889634f

typedef __attribute__((ext_vector_type(8))) short s16x8;
typedef __attribute__((ext_vector_type(4))) float f32x4;
typedef __attribute__((ext_vector_type(2))) unsigned int u32x2;
typedef __attribute__((ext_vector_type(4))) unsigned int u32x4;

static __device__ __forceinline__ unsigned cvtpk(float a, float b) {
    unsigned d;
    asm("v_cvt_pk_bf16_f32 %0, %1, %2" : "=v"(d) : "v"(a), "v"(b));
    return d;
}
static __device__ __forceinline__ short f2b(float f) {
    union { float f; unsigned u; } v; v.f = f;
    return (short)((v.u + 0x7FFFu + ((v.u >> 16) & 1u)) >> 16);
}
static __device__ __forceinline__ float b2f(short s) {
    union { unsigned u; float f; } v; v.u = ((unsigned)(unsigned short)s) << 16;
    return v.f;
}

// ---------------------------------------------------------------------------
// K0: 1x1 conv projections, one projection per blockIdx.y.
//  y=0: kC[b][c][n] (bf16)   y=1: vT[b][n][c]   y=2: qT[b][n][c] * log2(e)
// ---------------------------------------------------------------------------
__global__ __launch_bounds__(128) void k_proj(
    const float* __restrict__ xA, const float* __restrict__ xB,
    const float* __restrict__ Wk, const float* __restrict__ bk,
    const float* __restrict__ Wv, const float* __restrict__ bv,
    const float* __restrict__ Wq, const float* __restrict__ bq,
    short* __restrict__ vT, short* __restrict__ qT, short* __restrict__ kC)
{
    int mode = blockIdx.y;
    const float* W    = mode == 0 ? Wk : (mode == 1 ? Wv : Wq);
    const float* bias = mode == 0 ? bk : (mode == 1 ? bv : bq);
    const float* X    = mode == 2 ? xB : xA;

    __shared__ float sW[CI * CC];
    __shared__ float sb[CI];
    for (int i = threadIdx.x; i < CI * CC; i += 128) sW[i] = W[i];
    if (threadIdx.x < CI) sb[threadIdx.x] = bias[threadIdx.x];
    __syncthreads();

    int idx = blockIdx.x * 128 + threadIdx.x;   // 0 .. NBATCH*NPIX-1
    int b = idx / NPIX, n = idx % NPIX;

    float acc[CI];
    #pragma unroll
    for (int o = 0; o < CI; o++) acc[o] = sb[o];

    const float* px = X + (size_t)b * CC * NPIX + n;
    for (int c = 0; c < CC; c++) {
        float x = px[(size_t)c * NPIX];
        #pragma unroll
        for (int o = 0; o < CI; o++) acc[o] += sW[o * CC + c] * x;
    }

    if (mode == 0) {
        #pragma unroll
        for (int o = 0; o < CI; o++)
            kC[((size_t)b * CI + o) * NPIX + n] = f2b(acc[o]);
    } else {
        float sc = (mode == 2) ? LOG2E : 1.0f;
        short* dst = (mode == 1 ? vT : qT) + ((size_t)b * NPIX + n) * CI;
        #pragma unroll
        for (int q4 = 0; q4 < 4; q4++) {
            u32x4 pk;
            #pragma unroll
            for (int j = 0; j < 4; j++)
                pk[j] = cvtpk(acc[q4 * 8 + 2 * j] * sc, acc[q4 * 8 + 2 * j + 1] * sc);
            ((u32x4*)dst)[q4] = pk;
        }
    }
}

// ---------------------------------------------------------------------------
// K1: sum_part[z][b][n] = sum over m-slice of exp2(S'[n,m]).
// Per wave: 32 fixed n-rows, loop m in 32-col chunks (4 MFMA + 16 exp /iter).
// ---------------------------------------------------------------------------
__global__ __launch_bounds__(128) void k_denom(
    const short* __restrict__ vT, const short* __restrict__ qT,
    float* __restrict__ sum_part)
{
    int w = threadIdx.x >> 6, lane = threadIdx.x & 63;
    int r = lane & 15, g = lane >> 4;
    int b = blockIdx.y;
    int nb = blockIdx.x * 64 + w * 32;

    const short* vb = vT + (size_t)b * NPIX * CI;
    s16x8 a0 = *(const s16x8*)(vb + (size_t)(nb + r) * CI + 8 * g);
    s16x8 a1 = *(const s16x8*)(vb + (size_t)(nb + 16 + r) * CI + 8 * g);

    f32x4 s0 = {0.f, 0.f, 0.f, 0.f}, s1 = {0.f, 0.f, 0.f, 0.f};
    f32x4 z  = {0.f, 0.f, 0.f, 0.f};
    const short* qb = qT + (size_t)b * NPIX * CI;
    int mlo = blockIdx.z * (NPIX / NSD);
    int mhi = mlo + NPIX / NSD;
    for (int m0 = mlo; m0 < mhi; m0 += 32) {
        s16x8 q0 = *(const s16x8*)(qb + (size_t)(m0 + r) * CI + 8 * g);
        s16x8 q1 = *(const s16x8*)(qb + (size_t)(m0 + 16 + r) * CI + 8 * g);
        f32x4 t00 = __builtin_amdgcn_mfma_f32_16x16x32_bf16(a0, q0, z, 0, 0, 0);
        f32x4 t01 = __builtin_amdgcn_mfma_f32_16x16x32_bf16(a0, q1, z, 0, 0, 0);
        f32x4 t10 = __builtin_amdgcn_mfma_f32_16x16x32_bf16(a1, q0, z, 0, 0, 0);
        f32x4 t11 = __builtin_amdgcn_mfma_f32_16x16x32_bf16(a1, q1, z, 0, 0, 0);
        #pragma unroll
        for (int e = 0; e < 4; e++) {
            s0[e] += __builtin_amdgcn_exp2f(t00[e]) + __builtin_amdgcn_exp2f(t01[e]);
            s1[e] += __builtin_amdgcn_exp2f(t10[e]) + __builtin_amdgcn_exp2f(t11[e]);
        }
    }
    #pragma unroll
    for (int mask = 1; mask < 16; mask <<= 1) {
        #pragma unroll
        for (int e = 0; e < 4; e++) {
            s0[e] += __shfl_xor(s0[e], mask, 64);
            s1[e] += __shfl_xor(s1[e], mask, 64);
        }
    }
    if (r == 0) {
        float* sp = sum_part + ((size_t)blockIdx.z * NBATCH + b) * NPIX;
        #pragma unroll
        for (int e = 0; e < 4; e++) {
            sp[nb + 4 * g + e]      = s0[e];
            sp[nb + 16 + 4 * g + e] = s1[e];
        }
    }
}

// ---------------------------------------------------------------------------
// K1b: nl2d[b][n] = -log2( sum_z sum_part[z][b][n] )
// ---------------------------------------------------------------------------
__global__ __launch_bounds__(256) void k_l2d(
    const float* __restrict__ sum_part, float* __restrict__ nl2d)
{
    int idx = blockIdx.x * 256 + threadIdx.x;   // b*NPIX + n
    float s = 0.f;
    #pragma unroll
    for (int zz = 0; zz < NSD; zz++)
        s += sum_part[(size_t)zz * NBATCH * NPIX + idx];
    nl2d[idx] = -__builtin_amdgcn_logf(s);
}

// ---------------------------------------------------------------------------
// K2: avp[z][b][m][c] (bf16) = sum over n-slice of k[c,n] * P[n,m],
//     P = exp2(S' - log2 denom) computed with -log2d as the MFMA C-operand.
// Per wave: 32 m-cols fixed, loop n in 32-row chunks: 8 MFMA / iter.
// ---------------------------------------------------------------------------
__global__ __launch_bounds__(128) void k_attn(
    const short* __restrict__ vT, const short* __restrict__ qT,
    const short* __restrict__ kC, const float* __restrict__ nl2d,
    short* __restrict__ avp)
{
    __shared__ __align__(16) short plds[2][32][40];  // [wave][m-local][n-local+pad]
    int w = threadIdx.x >> 6, lane = threadIdx.x & 63;
    int r = lane & 15, g = lane >> 4;
    int b = blockIdx.y;
    int m0 = blockIdx.x * 64 + w * 32;

    const short* qb = qT + (size_t)b * NPIX * CI;
    s16x8 qb0 = *(const s16x8*)(qb + (size_t)(m0 + r) * CI + 8 * g);
    s16x8 qb1 = *(const s16x8*)(qb + (size_t)(m0 + 16 + r) * CI + 8 * g);

    const short* vb = vT + (size_t)b * NPIX * CI;
    const short* k0 = kC + ((size_t)b * CI + r) * NPIX;
    const short* k1 = k0 + (size_t)16 * NPIX;
    const float* nl2 = nl2d + (size_t)b * NPIX;

    f32x4 acc00 = {0,0,0,0}, acc01 = {0,0,0,0}, acc10 = {0,0,0,0}, acc11 = {0,0,0,0};

    int nlo = blockIdx.z * (NPIX / NSA);
    int nhi = nlo + NPIX / NSA;
    for (int n0 = nlo; n0 < nhi; n0 += 32) {
        f32x4 c0 = *(const f32x4*)(nl2 + n0 + 4 * g);        // rows n0+4g+e
        f32x4 c1 = *(const f32x4*)(nl2 + n0 + 16 + 4 * g);   // rows n0+16+4g+e
        s16x8 a0 = *(const s16x8*)(vb + (size_t)(n0 + r) * CI + 8 * g);
        s16x8 a1 = *(const s16x8*)(vb + (size_t)(n0 + 16 + r) * CI + 8 * g);

        f32x4 t00 = __builtin_amdgcn_mfma_f32_16x16x32_bf16(a0, qb0, c0, 0, 0, 0);
        f32x4 t01 = __builtin_amdgcn_mfma_f32_16x16x32_bf16(a0, qb1, c0, 0, 0, 0);
        f32x4 t10 = __builtin_amdgcn_mfma_f32_16x16x32_bf16(a1, qb0, c1, 0, 0, 0);
        f32x4 t11 = __builtin_amdgcn_mfma_f32_16x16x32_bf16(a1, qb1, c1, 0, 0, 0);

        u32x2 w00 = {cvtpk(__builtin_amdgcn_exp2f(t00[0]), __builtin_amdgcn_exp2f(t00[1])),
                     cvtpk(__builtin_amdgcn_exp2f(t00[2]), __builtin_amdgcn_exp2f(t00[3]))};
        u32x2 w10 = {cvtpk(__builtin_amdgcn_exp2f(t10[0]), __builtin_amdgcn_exp2f(t10[1])),
                     cvtpk(__builtin_amdgcn_exp2f(t10[2]), __builtin_amdgcn_exp2f(t10[3]))};
        u32x2 w01 = {cvtpk(__builtin_amdgcn_exp2f(t01[0]), __builtin_amdgcn_exp2f(t01[1])),
                     cvtpk(__builtin_amdgcn_exp2f(t01[2]), __builtin_amdgcn_exp2f(t01[3]))};
        u32x2 w11 = {cvtpk(__builtin_amdgcn_exp2f(t11[0]), __builtin_amdgcn_exp2f(t11[1])),
                     cvtpk(__builtin_amdgcn_exp2f(t11[2]), __builtin_amdgcn_exp2f(t11[3]))};

        // P tile [m-local][n-local]: rows m=r (qb0) and 16+r (qb1)
        *(u32x2*)&plds[w][r][4 * g]           = w00;
        *(u32x2*)&plds[w][r][16 + 4 * g]      = w10;
        *(u32x2*)&plds[w][16 + r][4 * g]      = w01;
        *(u32x2*)&plds[w][16 + r][16 + 4 * g] = w11;

        s16x8 pb0 = *(const s16x8*)&plds[w][r][8 * g];        // B-frag, m-half 0
        s16x8 pb1 = *(const s16x8*)&plds[w][16 + r][8 * g];   // B-frag, m-half 1
        s16x8 ka0 = *(const s16x8*)(k0 + n0 + 8 * g);         // A-frag, c 0-15
        s16x8 ka1 = *(const s16x8*)(k1 + n0 + 8 * g);         // A-frag, c 16-31

        acc00 = __builtin_amdgcn_mfma_f32_16x16x32_bf16(ka0, pb0, acc00, 0, 0, 0);
        acc10 = __builtin_amdgcn_mfma_f32_16x16x32_bf16(ka1, pb0, acc10, 0, 0, 0);
        acc01 = __builtin_amdgcn_mfma_f32_16x16x32_bf16(ka0, pb1, acc01, 0, 0, 0);
        acc11 = __builtin_amdgcn_mfma_f32_16x16x32_bf16(ka1, pb1, acc11, 0, 0, 0);
    }

    short* dst = avp + ((size_t)blockIdx.z * NBATCH + b) * NPIX * CI;
    u32x2 o00 = {cvtpk(acc00[0], acc00[1]), cvtpk(acc00[2], acc00[3])};
    u32x2 o10 = {cvtpk(acc10[0], acc10[1]), cvtpk(acc10[2], acc10[3])};
    u32x2 o01 = {cvtpk(acc01[0], acc01[1]), cvtpk(acc01[2], acc01[3])};
    u32x2 o11 = {cvtpk(acc11[0], acc11[1]), cvtpk(acc11[2], acc11[3])};
    *(u32x2*)(dst + (size_t)(m0 + r) * CI + 4 * g)           = o00;  // c=4g+e
    *(u32x2*)(dst + (size_t)(m0 + r) * CI + 16 + 4 * g)      = o10;  // c=16+4g+e
    *(u32x2*)(dst + (size_t)(m0 + 16 + r) * CI + 4 * g)      = o01;
    *(u32x2*)(dst + (size_t)(m0 + 16 + r) * CI + 16 + 4 * g) = o11;
}

// ---------------------------------------------------------------------------
// E1: a2[b][m][o] (bf16) = BN1( Wg @ (sum_z avp) )
// ---------------------------------------------------------------------------
__global__ __launch_bounds__(64) void k_e1(
    const short* __restrict__ avp, const float* __restrict__ Wg,
    const float* __restrict__ g1g, const float* __restrict__ g1b,
    const float* __restrict__ g1m, const float* __restrict__ g1v,
    short* __restrict__ a2buf)
{
    __shared__ float sWg[CI * CI], s1[CI], t1[CI];
    int t = threadIdx.x;
    for (int i = t; i < CI * CI; i += 64) sWg[i] = Wg[i];
    if (t < CI) {
        float s = g1g[t] * rsqrtf(g1v[t] + 1e-5f);
        s1[t] = s; t1[t] = g1b[t] - g1m[t] * s;
    }
    __syncthreads();

    int idx = blockIdx.x * 64 + t;   // b*NPIX + m
    float a[CI];
    #pragma unroll
    for (int c = 0; c < CI; c++) a[c] = 0.f;
    #pragma unroll
    for (int zz = 0; zz < NSA; zz++) {
        const short* p = avp + ((size_t)zz * NBATCH * NPIX + idx) * CI;
        #pragma unroll
        for (int v8 = 0; v8 < 4; v8++) {
            s16x8 tv = *(const s16x8*)(p + 8 * v8);
            #pragma unroll
            for (int j = 0; j < 8; j++) a[8 * v8 + j] += b2f(tv[j]);
        }
    }
    float a2[CI];
    #pragma unroll
    for (int o = 0; o < CI; o++) {
        float acc = 0.f;
        #pragma unroll
        for (int c = 0; c < CI; c++) acc += sWg[o * CI + c] * a[c];
        a2[o] = acc * s1[o] + t1[o];
    }
    short* dst = a2buf + (size_t)idx * CI;
    #pragma unroll
    for (int q4 = 0; q4 < 4; q4++) {
        u32x4 pk;
        #pragma unroll
        for (int j = 0; j < 4; j++)
            pk[j] = cvtpk(a2[q4 * 8 + 2 * j], a2[q4 * 8 + 2 * j + 1]);
        ((u32x4*)dst)[q4] = pk;
    }
}

// ---------------------------------------------------------------------------
// E2: out = relu( BN2( Wo @ a2 + bo ) + xB ), 32 output channels per y-block
// ---------------------------------------------------------------------------
__global__ __launch_bounds__(64) void k_e2(
    const short* __restrict__ a2buf,
    const float* __restrict__ Wo, const float* __restrict__ bo,
    const float* __restrict__ g2g, const float* __restrict__ g2b,
    const float* __restrict__ g2m, const float* __restrict__ g2v,
    const float* __restrict__ xB, float* __restrict__ out)
{
    __shared__ float sWo[32 * CI], s2[32], t2[32];
    int t = threadIdx.x, jh = blockIdx.y;
    for (int i = t; i < 32 * CI; i += 64) sWo[i] = Wo[jh * 32 * CI + i];
    if (t < 32) {
        int j = jh * 32 + t;
        float s = g2g[j] * rsqrtf(g2v[j] + 1e-5f);
        s2[t] = s; t2[t] = g2b[j] - g2m[j] * s + bo[j] * s;
    }
    __syncthreads();

    int idx = blockIdx.x * 64 + t;   // b*NPIX + m
    int b = idx / NPIX, m = idx % NPIX;

    float a2[CI];
    const short* p = a2buf + (size_t)idx * CI;
    #pragma unroll
    for (int v8 = 0; v8 < 4; v8++) {
        s16x8 tv = *(const s16x8*)(p + 8 * v8);
        #pragma unroll
        for (int j = 0; j < 8; j++) a2[8 * v8 + j] = b2f(tv[j]);
    }
    #pragma unroll
    for (int jj = 0; jj < 32; jj++) {
        float acc = 0.f;
        #pragma unroll
        for (int o = 0; o < CI; o++) acc += sWo[jj * CI + o] * a2[o];
        acc = acc * s2[jj] + t2[jj];
        size_t oi = ((size_t)b * CC + jh * 32 + jj) * NPIX + m;
        float res = acc + xB[oi];
        out[oi] = res > 0.f ? res : 0.f;
    }
}

// ---------------------------------------------------------------------------
extern "C" void kernel_launch(void* const* d_in, const int* in_sizes, int n_in,
                              void* d_out, int out_size, void* d_ws, size_t ws_size,
                              hipStream_t stream)
{
    const float* xA = (const float*)d_in[0];
    const float* xB = (const float*)d_in[1];
    const float* Wk = (const float*)d_in[2];
    const float* bk = (const float*)d_in[3];
    const float* Wv = (const float*)d_in[4];
    const float* bv = (const float*)d_in[5];
    const float* Wq = (const float*)d_in[6];
    const float* bq = (const float*)d_in[7];
    const float* Wg = (const float*)d_in[8];
    const float* g1g = (const float*)d_in[9];
    const float* g1b = (const float*)d_in[10];
    const float* g1m = (const float*)d_in[11];
    const float* g1v = (const float*)d_in[12];
    const float* Wo = (const float*)d_in[13];
    const float* bo = (const float*)d_in[14];
    const float* g2g = (const float*)d_in[15];
    const float* g2b = (const float*)d_in[16];
    const float* g2m = (const float*)d_in[17];
    const float* g2v = (const float*)d_in[18];
    float* out = (float*)d_out;

    char* ws = (char*)d_ws;
    const size_t SZB = (size_t)NBATCH * NPIX * CI * 2;      // 1,179,648 B
    short* vT = (short*)(ws);                                // dead after k_attn
    short* qT = (short*)(ws + SZB);
    short* kC = (short*)(ws + 2 * SZB);
    float* nl2d = (float*)(ws + 3 * SZB);                    // NBATCH*NPIX f32 = 73,728 B
    char*  region = ws + 3 * SZB + (size_t)NBATCH * NPIX * 4;
    float* sum_part = (float*)region;                        // NSD*NBATCH*NPIX f32 (dead after k_l2d)
    short* avp = (short*)region;                             // NSA*NBATCH*NPIX*CI bf16 (overlays sum_part)
    short* a2buf = vT;                                       // overlays vT after k_attn

    k_proj<<<dim3(NBATCH * NPIX / 128, 3), dim3(128), 0, stream>>>(
        xA, xB, Wk, bk, Wv, bv, Wq, bq, vT, qT, kC);
    k_denom<<<dim3(NPIX / 64, NBATCH, NSD), dim3(128), 0, stream>>>(
        vT, qT, sum_part);
    k_l2d<<<dim3(NBATCH * NPIX / 256), dim3(256), 0, stream>>>(
        sum_part, nl2d);
    k_attn<<<dim3(NPIX / 64, NBATCH, NSA), dim3(128), 0, stream>>>(
        vT, qT, kC, nl2d, avp);
    k_e1<<<dim3(NBATCH * NPIX / 64), dim3(64), 0, stream>>>(
        avp, Wg, g1g, g1b, g1m, g1v, a2buf);
    k_e2<<<dim3(NBATCH * NPIX / 64, 2), dim3(64), 0, stream>>>(
        a2buf, Wo, bo, g2g, g2b, g2m, g2v, xB, out);
}

// Round 4
// 140.189 us; speedup vs baseline: 1.9774x; 1.1016x over previous
//
#include <hip/hip_runtime.h>
#include <hip/hip_bf16.h>

#define CI 32
#define CC 64
#define NBATCH 2
#define NPIX 9216          // 96*96
#define NSD 16             // m-splits for k_denom
#define LOG2E 1.4426950408889634f

typedef __attribute__((ext_vector_type(8))) short s16x8;
typedef __attribute__((ext_vector_type(4))) short s16x4;
typedef __attribute__((ext_vector_type(4))) float f32x4;
typedef __attribute__((ext_vector_type(2))) unsigned int u32x2;
typedef __attribute__((ext_vector_type(4))) unsigned int u32x4;

static __device__ __forceinline__ unsigned cvtpk(float a, float b) {
    unsigned d;
    asm("v_cvt_pk_bf16_f32 %0, %1, %2" : "=v"(d) : "v"(a), "v"(b));
    return d;
}
static __device__ __forceinline__ short f2b(float f) {
    union { float f; unsigned u; } v; v.f = f;
    return (short)((v.u + 0x7FFFu + ((v.u >> 16) & 1u)) >> 16);
}
static __device__ __forceinline__ float b2f(short s) {
    union { unsigned u; float f; } v; v.u = ((unsigned)(unsigned short)s) << 16;
    return v.f;
}

// ---------------------------------------------------------------------------
// K0: 1x1 conv projections. grid (NBATCH*NPIX/64, 3). 256 thr: 4-way c-split
// per pixel (quarter q4 handles 16 input channels), combine via LDS.
//  mode 0: kC[b][c][n]   mode 1: vT[b][n][c]   mode 2: qT[b][n][c] * log2(e)
// ---------------------------------------------------------------------------
__global__ __launch_bounds__(256) void k_proj(
    const float* __restrict__ xA, const float* __restrict__ xB,
    const float* __restrict__ Wk, const float* __restrict__ bk,
    const float* __restrict__ Wv, const float* __restrict__ bv,
    const float* __restrict__ Wq, const float* __restrict__ bq,
    short* __restrict__ vT, short* __restrict__ qT, short* __restrict__ kC)
{
    int mode = blockIdx.y;
    const float* W    = mode == 0 ? Wk : (mode == 1 ? Wv : Wq);
    const float* bias = mode == 0 ? bk : (mode == 1 ? bv : bq);
    const float* X    = mode == 2 ? xB : xA;

    __shared__ float sW[CI * CC];
    __shared__ float sb[CI];
    __shared__ float spart[3][64][33];
    for (int i = threadIdx.x; i < CI * CC; i += 256) sW[i] = W[i];
    if (threadIdx.x < CI) sb[threadIdx.x] = bias[threadIdx.x];
    __syncthreads();

    int q4 = threadIdx.x >> 6;      // c-quarter
    int lp = threadIdx.x & 63;      // local pixel
    int idx = blockIdx.x * 64 + lp; // 0 .. NBATCH*NPIX-1
    int b = idx / NPIX, n = idx % NPIX;

    float acc[CI];
    #pragma unroll
    for (int o = 0; o < CI; o++) acc[o] = 0.f;

    const float* px = X + (size_t)b * CC * NPIX + n;
    #pragma unroll
    for (int cc = 0; cc < 16; cc++) {
        int c = q4 * 16 + cc;
        float x = px[(size_t)c * NPIX];
        #pragma unroll
        for (int o = 0; o < CI; o++) acc[o] += sW[o * CC + c] * x;
    }
    if (q4) {
        #pragma unroll
        for (int o = 0; o < CI; o++) spart[q4 - 1][lp][o] = acc[o];
    }
    __syncthreads();
    if (q4 == 0) {
        #pragma unroll
        for (int o = 0; o < CI; o++)
            acc[o] += spart[0][lp][o] + spart[1][lp][o] + spart[2][lp][o] + sb[o];
        if (mode == 0) {
            #pragma unroll
            for (int o = 0; o < CI; o++)
                kC[((size_t)b * CI + o) * NPIX + n] = f2b(acc[o]);
        } else {
            float sc = (mode == 2) ? LOG2E : 1.0f;
            short* dst = (mode == 1 ? vT : qT) + ((size_t)b * NPIX + n) * CI;
            #pragma unroll
            for (int v4 = 0; v4 < 4; v4++) {
                u32x4 pk;
                #pragma unroll
                for (int j = 0; j < 4; j++)
                    pk[j] = cvtpk(acc[v4 * 8 + 2 * j] * sc, acc[v4 * 8 + 2 * j + 1] * sc);
                ((u32x4*)dst)[v4] = pk;
            }
        }
    }
}

// ---------------------------------------------------------------------------
// K1: sum_part[z][b][n] = sum over m-slice of exp2(S'[n,m]).
// ---------------------------------------------------------------------------
__global__ __launch_bounds__(128) void k_denom(
    const short* __restrict__ vT, const short* __restrict__ qT,
    float* __restrict__ sum_part)
{
    int w = threadIdx.x >> 6, lane = threadIdx.x & 63;
    int r = lane & 15, g = lane >> 4;
    int b = blockIdx.y;
    int nb = blockIdx.x * 64 + w * 32;

    const short* vb = vT + (size_t)b * NPIX * CI;
    s16x8 a0 = *(const s16x8*)(vb + (size_t)(nb + r) * CI + 8 * g);
    s16x8 a1 = *(const s16x8*)(vb + (size_t)(nb + 16 + r) * CI + 8 * g);

    f32x4 s0 = {0.f, 0.f, 0.f, 0.f}, s1 = {0.f, 0.f, 0.f, 0.f};
    f32x4 z  = {0.f, 0.f, 0.f, 0.f};
    const short* qb = qT + (size_t)b * NPIX * CI;
    int mlo = blockIdx.z * (NPIX / NSD);
    int mhi = mlo + NPIX / NSD;
    for (int m0 = mlo; m0 < mhi; m0 += 32) {
        s16x8 q0 = *(const s16x8*)(qb + (size_t)(m0 + r) * CI + 8 * g);
        s16x8 q1 = *(const s16x8*)(qb + (size_t)(m0 + 16 + r) * CI + 8 * g);
        f32x4 t00 = __builtin_amdgcn_mfma_f32_16x16x32_bf16(a0, q0, z, 0, 0, 0);
        f32x4 t01 = __builtin_amdgcn_mfma_f32_16x16x32_bf16(a0, q1, z, 0, 0, 0);
        f32x4 t10 = __builtin_amdgcn_mfma_f32_16x16x32_bf16(a1, q0, z, 0, 0, 0);
        f32x4 t11 = __builtin_amdgcn_mfma_f32_16x16x32_bf16(a1, q1, z, 0, 0, 0);
        #pragma unroll
        for (int e = 0; e < 4; e++) {
            s0[e] += __builtin_amdgcn_exp2f(t00[e]) + __builtin_amdgcn_exp2f(t01[e]);
            s1[e] += __builtin_amdgcn_exp2f(t10[e]) + __builtin_amdgcn_exp2f(t11[e]);
        }
    }
    #pragma unroll
    for (int mask = 1; mask < 16; mask <<= 1) {
        #pragma unroll
        for (int e = 0; e < 4; e++) {
            s0[e] += __shfl_xor(s0[e], mask, 64);
            s1[e] += __shfl_xor(s1[e], mask, 64);
        }
    }
    if (r == 0) {
        float* sp = sum_part + ((size_t)blockIdx.z * NBATCH + b) * NPIX;
        #pragma unroll
        for (int e = 0; e < 4; e++) {
            sp[nb + 4 * g + e]      = s0[e];
            sp[nb + 16 + 4 * g + e] = s1[e];
        }
    }
}

// ---------------------------------------------------------------------------
// K1b: invd[b][n] = 1 / sum_z sum_part[z][b][n]
// ---------------------------------------------------------------------------
__global__ __launch_bounds__(256) void k_invd(
    const float* __restrict__ sum_part, float* __restrict__ invd)
{
    int idx = blockIdx.x * 256 + threadIdx.x;   // b*NPIX + n
    float s = 0.f;
    #pragma unroll
    for (int zz = 0; zz < NSD; zz++)
        s += sum_part[(size_t)zz * NBATCH * NPIX + idx];
    invd[idx] = 1.0f / s;
}

// ---------------------------------------------------------------------------
// K1c: kC[b][c][n] *= invd[b][n]
// ---------------------------------------------------------------------------
__global__ __launch_bounds__(256) void k_scale(
    short* __restrict__ kC, const float* __restrict__ invd)
{
    int idx = blockIdx.x * 256 + threadIdx.x;   // (b*CI+c)*NPIX + n
    int n = idx % NPIX;
    int b = idx / (CI * NPIX);
    kC[idx] = f2b(b2f(kC[idx]) * invd[b * NPIX + n]);
}

// ---------------------------------------------------------------------------
// K2: avp[z][b][m][c] (bf16) = sum over n-slice of k'[c,n] * exp2(S'[n,m])
// Per wave: 32 m-cols fixed, loop n in 32-row chunks: 8 MFMA / iter.
// ---------------------------------------------------------------------------
__global__ __launch_bounds__(128) void k_attn(
    const short* __restrict__ vT, const short* __restrict__ qT,
    const short* __restrict__ kC, short* __restrict__ avp, int slice)
{
    __shared__ short plds[2][32][36];  // [wave][m-local][n-local], stride 36
    int w = threadIdx.x >> 6, lane = threadIdx.x & 63;
    int r = lane & 15, g = lane >> 4;
    int b = blockIdx.y;
    int m0 = blockIdx.x * 64 + w * 32;

    const short* qb = qT + (size_t)b * NPIX * CI;
    s16x8 qb0 = *(const s16x8*)(qb + (size_t)(m0 + r) * CI + 8 * g);
    s16x8 qb1 = *(const s16x8*)(qb + (size_t)(m0 + 16 + r) * CI + 8 * g);

    const short* vb = vT + (size_t)b * NPIX * CI;
    const short* k0 = kC + ((size_t)b * CI + r) * NPIX;
    const short* k1 = k0 + (size_t)16 * NPIX;

    f32x4 acc00 = {0,0,0,0}, acc01 = {0,0,0,0}, acc10 = {0,0,0,0}, acc11 = {0,0,0,0};
    f32x4 z = {0,0,0,0};

    int nlo = blockIdx.z * slice;
    int nhi = nlo + slice;
    for (int n0 = nlo; n0 < nhi; n0 += 32) {
        s16x8 a0  = *(const s16x8*)(vb + (size_t)(n0 + r) * CI + 8 * g);
        s16x8 a1  = *(const s16x8*)(vb + (size_t)(n0 + 16 + r) * CI + 8 * g);
        s16x8 ka0 = *(const s16x8*)(k0 + n0 + 8 * g);
        s16x8 ka1 = *(const s16x8*)(k1 + n0 + 8 * g);

        f32x4 t00 = __builtin_amdgcn_mfma_f32_16x16x32_bf16(a0, qb0, z, 0, 0, 0);
        f32x4 t01 = __builtin_amdgcn_mfma_f32_16x16x32_bf16(a0, qb1, z, 0, 0, 0);
        f32x4 t10 = __builtin_amdgcn_mfma_f32_16x16x32_bf16(a1, qb0, z, 0, 0, 0);
        f32x4 t11 = __builtin_amdgcn_mfma_f32_16x16x32_bf16(a1, qb1, z, 0, 0, 0);

        u32x2 w00 = {cvtpk(__builtin_amdgcn_exp2f(t00[0]), __builtin_amdgcn_exp2f(t00[1])),
                     cvtpk(__builtin_amdgcn_exp2f(t00[2]), __builtin_amdgcn_exp2f(t00[3]))};
        u32x2 w10 = {cvtpk(__builtin_amdgcn_exp2f(t10[0]), __builtin_amdgcn_exp2f(t10[1])),
                     cvtpk(__builtin_amdgcn_exp2f(t10[2]), __builtin_amdgcn_exp2f(t10[3]))};
        u32x2 w01 = {cvtpk(__builtin_amdgcn_exp2f(t01[0]), __builtin_amdgcn_exp2f(t01[1])),
                     cvtpk(__builtin_amdgcn_exp2f(t01[2]), __builtin_amdgcn_exp2f(t01[3]))};
        u32x2 w11 = {cvtpk(__builtin_amdgcn_exp2f(t11[0]), __builtin_amdgcn_exp2f(t11[1])),
                     cvtpk(__builtin_amdgcn_exp2f(t11[2]), __builtin_amdgcn_exp2f(t11[3]))};

        // P tile [m-local][n-local]
        *(u32x2*)&plds[w][r][4 * g]           = w00;
        *(u32x2*)&plds[w][r][16 + 4 * g]      = w10;
        *(u32x2*)&plds[w][16 + r][4 * g]      = w01;
        *(u32x2*)&plds[w][16 + r][16 + 4 * g] = w11;

        s16x4 l0 = *(const s16x4*)&plds[w][r][8 * g];
        s16x4 h0 = *(const s16x4*)&plds[w][r][8 * g + 4];
        s16x4 l1 = *(const s16x4*)&plds[w][16 + r][8 * g];
        s16x4 h1 = *(const s16x4*)&plds[w][16 + r][8 * g + 4];
        s16x8 pb0 = {l0[0], l0[1], l0[2], l0[3], h0[0], h0[1], h0[2], h0[3]};
        s16x8 pb1 = {l1[0], l1[1], l1[2], l1[3], h1[0], h1[1], h1[2], h1[3]};

        acc00 = __builtin_amdgcn_mfma_f32_16x16x32_bf16(ka0, pb0, acc00, 0, 0, 0);
        acc10 = __builtin_amdgcn_mfma_f32_16x16x32_bf16(ka1, pb0, acc10, 0, 0, 0);
        acc01 = __builtin_amdgcn_mfma_f32_16x16x32_bf16(ka0, pb1, acc01, 0, 0, 0);
        acc11 = __builtin_amdgcn_mfma_f32_16x16x32_bf16(ka1, pb1, acc11, 0, 0, 0);
    }

    short* dst = avp + ((size_t)blockIdx.z * NBATCH + b) * NPIX * CI;
    u32x2 o00 = {cvtpk(acc00[0], acc00[1]), cvtpk(acc00[2], acc00[3])};
    u32x2 o10 = {cvtpk(acc10[0], acc10[1]), cvtpk(acc10[2], acc10[3])};
    u32x2 o01 = {cvtpk(acc01[0], acc01[1]), cvtpk(acc01[2], acc01[3])};
    u32x2 o11 = {cvtpk(acc11[0], acc11[1]), cvtpk(acc11[2], acc11[3])};
    *(u32x2*)(dst + (size_t)(m0 + r) * CI + 4 * g)           = o00;
    *(u32x2*)(dst + (size_t)(m0 + r) * CI + 16 + 4 * g)      = o10;
    *(u32x2*)(dst + (size_t)(m0 + 16 + r) * CI + 4 * g)      = o01;
    *(u32x2*)(dst + (size_t)(m0 + 16 + r) * CI + 16 + 4 * g) = o11;
}

// ---------------------------------------------------------------------------
// E0: av[b][m][c] (bf16) = sum_z avp[z][b][m][c]; 8 channels per thread
// ---------------------------------------------------------------------------
__global__ __launch_bounds__(256) void e_red(
    const short* __restrict__ avp, short* __restrict__ av, int nsa)
{
    int vecidx = blockIdx.x * 256 + threadIdx.x;   // over NBATCH*NPIX*CI/8
    const short* src = avp + (size_t)vecidx * 8;
    float s[8];
    #pragma unroll
    for (int j = 0; j < 8; j++) s[j] = 0.f;
    for (int zz = 0; zz < nsa; zz++) {
        s16x8 t = *(const s16x8*)(src + (size_t)zz * NBATCH * NPIX * CI);
        #pragma unroll
        for (int j = 0; j < 8; j++) s[j] += b2f(t[j]);
    }
    u32x4 pk;
    #pragma unroll
    for (int j = 0; j < 4; j++) pk[j] = cvtpk(s[2 * j], s[2 * j + 1]);
    *(u32x4*)(av + (size_t)vecidx * 8) = pk;
}

// ---------------------------------------------------------------------------
// E1: out = relu( BN2( Wo @ BN1(Wg @ av) + bo ) + xB ), j-half per y-block
// ---------------------------------------------------------------------------
__global__ __launch_bounds__(256) void e_fused(
    const short* __restrict__ av,
    const float* __restrict__ Wg,
    const float* __restrict__ g1g, const float* __restrict__ g1b,
    const float* __restrict__ g1m, const float* __restrict__ g1v,
    const float* __restrict__ Wo, const float* __restrict__ bo,
    const float* __restrict__ g2g, const float* __restrict__ g2b,
    const float* __restrict__ g2m, const float* __restrict__ g2v,
    const float* __restrict__ xB, float* __restrict__ out)
{
    __shared__ float sWg[CI * CI], sWo[32 * CI], s1[CI], t1[CI], s2[32], t2[32];
    int t = threadIdx.x, jh = blockIdx.y;
    for (int i = t; i < CI * CI; i += 256) sWg[i] = Wg[i];
    for (int i = t; i < 32 * CI; i += 256) sWo[i] = Wo[jh * 32 * CI + i];
    if (t < CI) {
        float s = g1g[t] * rsqrtf(g1v[t] + 1e-5f);
        s1[t] = s; t1[t] = g1b[t] - g1m[t] * s;
    } else if (t < CI + 32) {
        int j = jh * 32 + (t - CI);
        float s = g2g[j] * rsqrtf(g2v[j] + 1e-5f);
        s2[t - CI] = s; t2[t - CI] = g2b[j] - g2m[j] * s + bo[j] * s;
    }
    __syncthreads();

    int idx = blockIdx.x * 256 + t;   // b*NPIX + m
    int b = idx / NPIX, m = idx % NPIX;

    float a[CI];
    const short* p = av + (size_t)idx * CI;
    #pragma unroll
    for (int v8 = 0; v8 < 4; v8++) {
        s16x8 tv = *(const s16x8*)(p + 8 * v8);
        #pragma unroll
        for (int j = 0; j < 8; j++) a[8 * v8 + j] = b2f(tv[j]);
    }
    float a2[CI];
    #pragma unroll
    for (int o = 0; o < CI; o++) {
        float acc = 0.f;
        #pragma unroll
        for (int c = 0; c < CI; c++) acc += sWg[o * CI + c] * a[c];
        a2[o] = acc * s1[o] + t1[o];
    }
    #pragma unroll
    for (int jj = 0; jj < 32; jj++) {
        float acc = 0.f;
        #pragma unroll
        for (int o = 0; o < CI; o++) acc += sWo[jj * CI + o] * a2[o];
        acc = acc * s2[jj] + t2[jj];
        size_t oi = ((size_t)b * CC + jh * 32 + jj) * NPIX + m;
        float res = acc + xB[oi];
        out[oi] = res > 0.f ? res : 0.f;
    }
}

// ---------------------------------------------------------------------------
extern "C" void kernel_launch(void* const* d_in, const int* in_sizes, int n_in,
                              void* d_out, int out_size, void* d_ws, size_t ws_size,
                              hipStream_t stream)
{
    const float* xA = (const float*)d_in[0];
    const float* xB = (const float*)d_in[1];
    const float* Wk = (const float*)d_in[2];
    const float* bk = (const float*)d_in[3];
    const float* Wv = (const float*)d_in[4];
    const float* bv = (const float*)d_in[5];
    const float* Wq = (const float*)d_in[6];
    const float* bq = (const float*)d_in[7];
    const float* Wg = (const float*)d_in[8];
    const float* g1g = (const float*)d_in[9];
    const float* g1b = (const float*)d_in[10];
    const float* g1m = (const float*)d_in[11];
    const float* g1v = (const float*)d_in[12];
    const float* Wo = (const float*)d_in[13];
    const float* bo = (const float*)d_in[14];
    const float* g2g = (const float*)d_in[15];
    const float* g2b = (const float*)d_in[16];
    const float* g2m = (const float*)d_in[17];
    const float* g2v = (const float*)d_in[18];
    float* out = (float*)d_out;

    char* ws = (char*)d_ws;
    const size_t SZB = (size_t)NBATCH * NPIX * CI * 2;       // 1,179,648 B
    short* vT = (short*)(ws);                                 // dead after k_attn
    short* qT = (short*)(ws + SZB);
    short* kC = (short*)(ws + 2 * SZB);
    float* invd = (float*)(ws + 3 * SZB);                     // NBATCH*NPIX f32
    char*  region = ws + 3 * SZB + (size_t)NBATCH * NPIX * 4;
    float* sum_part = (float*)region;                         // dead after k_invd
    short* avp = (short*)region;                              // overlays sum_part
    short* av = vT;                                           // overlays vT

    // pick attention n-split by available workspace
    const size_t base = 3 * SZB + (size_t)NBATCH * NPIX * 4;
    int nsa = (ws_size >= base + (size_t)16 * NBATCH * NPIX * CI * 2) ? 16 : 8;
    int slice = NPIX / nsa;

    k_proj<<<dim3(NBATCH * NPIX / 64, 3), dim3(256), 0, stream>>>(
        xA, xB, Wk, bk, Wv, bv, Wq, bq, vT, qT, kC);
    k_denom<<<dim3(NPIX / 64, NBATCH, NSD), dim3(128), 0, stream>>>(
        vT, qT, sum_part);
    k_invd<<<dim3(NBATCH * NPIX / 256), dim3(256), 0, stream>>>(
        sum_part, invd);
    k_scale<<<dim3(NBATCH * CI * NPIX / 256), dim3(256), 0, stream>>>(
        kC, invd);
    k_attn<<<dim3(NPIX / 64, NBATCH, nsa), dim3(128), 0, stream>>>(
        vT, qT, kC, avp, slice);
    e_red<<<dim3(NBATCH * NPIX * CI / 8 / 256), dim3(256), 0, stream>>>(
        avp, av, nsa);
    e_fused<<<dim3(NBATCH * NPIX / 256, 2), dim3(256), 0, stream>>>(
        av, Wg, g1g, g1b, g1m, g1v, Wo, bo, g2g, g2b, g2m, g2v, xB, out);
}

// Round 6
// 133.477 us; speedup vs baseline: 2.0768x; 1.0503x over previous
//
#include <hip/hip_runtime.h>
#include <hip/hip_bf16.h>

#define CI 32
#define CC 64
#define NBATCH 2
#define NPIX 9216          // 96*96
#define NSD 24             // m-splits for k_denom (NPIX/24 = 384 = 6*64)
#define LOG2E 1.4426950408889634f

typedef __attribute__((ext_vector_type(8))) short s16x8;
typedef __attribute__((ext_vector_type(4))) short s16x4;
typedef __attribute__((ext_vector_type(4))) float f32x4;
typedef __attribute__((ext_vector_type(2))) unsigned int u32x2;
typedef __attribute__((ext_vector_type(4))) unsigned int u32x4;

static __device__ __forceinline__ unsigned cvtpk(float a, float b) {
    unsigned d;
    asm("v_cvt_pk_bf16_f32 %0, %1, %2" : "=v"(d) : "v"(a), "v"(b));
    return d;
}
static __device__ __forceinline__ short f2b(float f) {
    union { float f; unsigned u; } v; v.f = f;
    return (short)((v.u + 0x7FFFu + ((v.u >> 16) & 1u)) >> 16);
}
static __device__ __forceinline__ float b2f(short s) {
    union { unsigned u; float f; } v; v.u = ((unsigned)(unsigned short)s) << 16;
    return v.f;
}

// ---------------------------------------------------------------------------
// K0: 1x1 conv projections. grid (NBATCH*NPIX/64, 3). 256 thr: 4-way c-split
// per pixel (quarter q4 handles 16 input channels), combine via LDS.
//  mode 0: kC[b][c][n]   mode 1: vT[b][n][c]   mode 2: qT[b][n][c] * log2(e)
// ---------------------------------------------------------------------------
__global__ __launch_bounds__(256) void k_proj(
    const float* __restrict__ xA, const float* __restrict__ xB,
    const float* __restrict__ Wk, const float* __restrict__ bk,
    const float* __restrict__ Wv, const float* __restrict__ bv,
    const float* __restrict__ Wq, const float* __restrict__ bq,
    short* __restrict__ vT, short* __restrict__ qT, short* __restrict__ kC)
{
    int mode = blockIdx.y;
    const float* W    = mode == 0 ? Wk : (mode == 1 ? Wv : Wq);
    const float* bias = mode == 0 ? bk : (mode == 1 ? bv : bq);
    const float* X    = mode == 2 ? xB : xA;

    __shared__ float sW[CI * CC];
    __shared__ float sb[CI];
    __shared__ float spart[3][64][33];
    for (int i = threadIdx.x; i < CI * CC; i += 256) sW[i] = W[i];
    if (threadIdx.x < CI) sb[threadIdx.x] = bias[threadIdx.x];
    __syncthreads();

    int q4 = threadIdx.x >> 6;      // c-quarter
    int lp = threadIdx.x & 63;      // local pixel
    int idx = blockIdx.x * 64 + lp; // 0 .. NBATCH*NPIX-1
    int b = idx / NPIX, n = idx % NPIX;

    float acc[CI];
    #pragma unroll
    for (int o = 0; o < CI; o++) acc[o] = 0.f;

    const float* px = X + (size_t)b * CC * NPIX + n;
    #pragma unroll
    for (int cc = 0; cc < 16; cc++) {
        int c = q4 * 16 + cc;
        float x = px[(size_t)c * NPIX];
        #pragma unroll
        for (int o = 0; o < CI; o++) acc[o] += sW[o * CC + c] * x;
    }
    if (q4) {
        #pragma unroll
        for (int o = 0; o < CI; o++) spart[q4 - 1][lp][o] = acc[o];
    }
    __syncthreads();
    if (q4 == 0) {
        #pragma unroll
        for (int o = 0; o < CI; o++)
            acc[o] += spart[0][lp][o] + spart[1][lp][o] + spart[2][lp][o] + sb[o];
        if (mode == 0) {
            #pragma unroll
            for (int o = 0; o < CI; o++)
                kC[((size_t)b * CI + o) * NPIX + n] = f2b(acc[o]);
        } else {
            float sc = (mode == 2) ? LOG2E : 1.0f;
            short* dst = (mode == 1 ? vT : qT) + ((size_t)b * NPIX + n) * CI;
            #pragma unroll
            for (int v4 = 0; v4 < 4; v4++) {
                u32x4 pk;
                #pragma unroll
                for (int j = 0; j < 4; j++)
                    pk[j] = cvtpk(acc[v4 * 8 + 2 * j] * sc, acc[v4 * 8 + 2 * j + 1] * sc);
                ((u32x4*)dst)[v4] = pk;
            }
        }
    }
}

// ---------------------------------------------------------------------------
// K1: sum_part[z][b][n] = sum over m-slice of exp2(S'[n,m]).
// Unrolled x2: two independent 32x32 chains in flight per wave.
// ---------------------------------------------------------------------------
__global__ __launch_bounds__(128) void k_denom(
    const short* __restrict__ vT, const short* __restrict__ qT,
    float* __restrict__ sum_part)
{
    int w = threadIdx.x >> 6, lane = threadIdx.x & 63;
    int r = lane & 15, g = lane >> 4;
    int b = blockIdx.y;
    int nb = blockIdx.x * 64 + w * 32;

    const short* vb = vT + (size_t)b * NPIX * CI;
    s16x8 a0 = *(const s16x8*)(vb + (size_t)(nb + r) * CI + 8 * g);
    s16x8 a1 = *(const s16x8*)(vb + (size_t)(nb + 16 + r) * CI + 8 * g);

    f32x4 s0 = {0.f, 0.f, 0.f, 0.f}, s1 = {0.f, 0.f, 0.f, 0.f};
    f32x4 s0b = {0.f, 0.f, 0.f, 0.f}, s1b = {0.f, 0.f, 0.f, 0.f};
    f32x4 z  = {0.f, 0.f, 0.f, 0.f};
    const short* qb = qT + (size_t)b * NPIX * CI;
    int mlo = blockIdx.z * (NPIX / NSD);
    int mhi = mlo + NPIX / NSD;
    for (int m0 = mlo; m0 < mhi; m0 += 64) {
        s16x8 q0 = *(const s16x8*)(qb + (size_t)(m0 + r) * CI + 8 * g);
        s16x8 q1 = *(const s16x8*)(qb + (size_t)(m0 + 16 + r) * CI + 8 * g);
        s16x8 q2 = *(const s16x8*)(qb + (size_t)(m0 + 32 + r) * CI + 8 * g);
        s16x8 q3 = *(const s16x8*)(qb + (size_t)(m0 + 48 + r) * CI + 8 * g);
        f32x4 t00 = __builtin_amdgcn_mfma_f32_16x16x32_bf16(a0, q0, z, 0, 0, 0);
        f32x4 t01 = __builtin_amdgcn_mfma_f32_16x16x32_bf16(a0, q1, z, 0, 0, 0);
        f32x4 t10 = __builtin_amdgcn_mfma_f32_16x16x32_bf16(a1, q0, z, 0, 0, 0);
        f32x4 t11 = __builtin_amdgcn_mfma_f32_16x16x32_bf16(a1, q1, z, 0, 0, 0);
        f32x4 u00 = __builtin_amdgcn_mfma_f32_16x16x32_bf16(a0, q2, z, 0, 0, 0);
        f32x4 u01 = __builtin_amdgcn_mfma_f32_16x16x32_bf16(a0, q3, z, 0, 0, 0);
        f32x4 u10 = __builtin_amdgcn_mfma_f32_16x16x32_bf16(a1, q2, z, 0, 0, 0);
        f32x4 u11 = __builtin_amdgcn_mfma_f32_16x16x32_bf16(a1, q3, z, 0, 0, 0);
        #pragma unroll
        for (int e = 0; e < 4; e++) {
            s0[e]  += __builtin_amdgcn_exp2f(t00[e]) + __builtin_amdgcn_exp2f(t01[e]);
            s1[e]  += __builtin_amdgcn_exp2f(t10[e]) + __builtin_amdgcn_exp2f(t11[e]);
            s0b[e] += __builtin_amdgcn_exp2f(u00[e]) + __builtin_amdgcn_exp2f(u01[e]);
            s1b[e] += __builtin_amdgcn_exp2f(u10[e]) + __builtin_amdgcn_exp2f(u11[e]);
        }
    }
    #pragma unroll
    for (int e = 0; e < 4; e++) { s0[e] += s0b[e]; s1[e] += s1b[e]; }
    #pragma unroll
    for (int mask = 1; mask < 16; mask <<= 1) {
        #pragma unroll
        for (int e = 0; e < 4; e++) {
            s0[e] += __shfl_xor(s0[e], mask, 64);
            s1[e] += __shfl_xor(s1[e], mask, 64);
        }
    }
    if (r == 0) {
        float* sp = sum_part + ((size_t)blockIdx.z * NBATCH + b) * NPIX;
        #pragma unroll
        for (int e = 0; e < 4; e++) {
            sp[nb + 4 * g + e]      = s0[e];
            sp[nb + 16 + 4 * g + e] = s1[e];
        }
    }
}

// ---------------------------------------------------------------------------
// K1b: invd[b][n] = 1 / sum_z sum_part[z][b][n]
// ---------------------------------------------------------------------------
__global__ __launch_bounds__(256) void k_invd(
    const float* __restrict__ sum_part, float* __restrict__ invd)
{
    int idx = blockIdx.x * 256 + threadIdx.x;   // b*NPIX + n
    float s = 0.f;
    #pragma unroll
    for (int zz = 0; zz < NSD; zz++)
        s += sum_part[(size_t)zz * NBATCH * NPIX + idx];
    invd[idx] = 1.0f / s;
}

// ---------------------------------------------------------------------------
// K1c: kC[b][c][n] *= invd[b][n]
// ---------------------------------------------------------------------------
__global__ __launch_bounds__(256) void k_scale(
    short* __restrict__ kC, const float* __restrict__ invd)
{
    int idx = blockIdx.x * 256 + threadIdx.x;   // (b*CI+c)*NPIX + n
    int n = idx % NPIX;
    int b = idx / (CI * NPIX);
    kC[idx] = f2b(b2f(kC[idx]) * invd[b * NPIX + n]);
}

// ---------------------------------------------------------------------------
// K2: avp[z][b][m][c] (bf16) = sum over n-slice of k'[c,n] * exp2(S'[n,m])
// Per wave: 32 m-cols fixed, n-loop unrolled x2 with double-buffered LDS:
// two independent QK->exp->pack->PV chains in flight.
// ---------------------------------------------------------------------------
__global__ __launch_bounds__(128) void k_attn(
    const short* __restrict__ vT, const short* __restrict__ qT,
    const short* __restrict__ kC, short* __restrict__ avp, int slice)
{
    __shared__ short plds[2][2][32][36];  // [wave][parity][m-local][n-local]
    int w = threadIdx.x >> 6, lane = threadIdx.x & 63;
    int r = lane & 15, g = lane >> 4;
    int b = blockIdx.y;
    int m0 = blockIdx.x * 64 + w * 32;

    const short* qb = qT + (size_t)b * NPIX * CI;
    s16x8 qb0 = *(const s16x8*)(qb + (size_t)(m0 + r) * CI + 8 * g);
    s16x8 qb1 = *(const s16x8*)(qb + (size_t)(m0 + 16 + r) * CI + 8 * g);

    const short* vb = vT + (size_t)b * NPIX * CI;
    const short* k0 = kC + ((size_t)b * CI + r) * NPIX;
    const short* k1 = k0 + (size_t)16 * NPIX;

    f32x4 acc00 = {0,0,0,0}, acc01 = {0,0,0,0}, acc10 = {0,0,0,0}, acc11 = {0,0,0,0};
    f32x4 z = {0,0,0,0};

    int nlo = blockIdx.z * slice;
    int nhi = nlo + slice;
    for (int n0 = nlo; n0 < nhi; n0 += 64) {
        #pragma unroll
        for (int par = 0; par < 2; par++) {
            int nn = n0 + par * 32;
            s16x8 a0  = *(const s16x8*)(vb + (size_t)(nn + r) * CI + 8 * g);
            s16x8 a1  = *(const s16x8*)(vb + (size_t)(nn + 16 + r) * CI + 8 * g);
            s16x8 ka0 = *(const s16x8*)(k0 + nn + 8 * g);
            s16x8 ka1 = *(const s16x8*)(k1 + nn + 8 * g);

            f32x4 t00 = __builtin_amdgcn_mfma_f32_16x16x32_bf16(a0, qb0, z, 0, 0, 0);
            f32x4 t01 = __builtin_amdgcn_mfma_f32_16x16x32_bf16(a0, qb1, z, 0, 0, 0);
            f32x4 t10 = __builtin_amdgcn_mfma_f32_16x16x32_bf16(a1, qb0, z, 0, 0, 0);
            f32x4 t11 = __builtin_amdgcn_mfma_f32_16x16x32_bf16(a1, qb1, z, 0, 0, 0);

            u32x2 w00 = {cvtpk(__builtin_amdgcn_exp2f(t00[0]), __builtin_amdgcn_exp2f(t00[1])),
                         cvtpk(__builtin_amdgcn_exp2f(t00[2]), __builtin_amdgcn_exp2f(t00[3]))};
            u32x2 w10 = {cvtpk(__builtin_amdgcn_exp2f(t10[0]), __builtin_amdgcn_exp2f(t10[1])),
                         cvtpk(__builtin_amdgcn_exp2f(t10[2]), __builtin_amdgcn_exp2f(t10[3]))};
            u32x2 w01 = {cvtpk(__builtin_amdgcn_exp2f(t01[0]), __builtin_amdgcn_exp2f(t01[1])),
                         cvtpk(__builtin_amdgcn_exp2f(t01[2]), __builtin_amdgcn_exp2f(t01[3]))};
            u32x2 w11 = {cvtpk(__builtin_amdgcn_exp2f(t11[0]), __builtin_amdgcn_exp2f(t11[1])),
                         cvtpk(__builtin_amdgcn_exp2f(t11[2]), __builtin_amdgcn_exp2f(t11[3]))};

            *(u32x2*)&plds[w][par][r][4 * g]           = w00;
            *(u32x2*)&plds[w][par][r][16 + 4 * g]      = w10;
            *(u32x2*)&plds[w][par][16 + r][4 * g]      = w01;
            *(u32x2*)&plds[w][par][16 + r][16 + 4 * g] = w11;

            s16x4 l0 = *(const s16x4*)&plds[w][par][r][8 * g];
            s16x4 h0 = *(const s16x4*)&plds[w][par][r][8 * g + 4];
            s16x4 l1 = *(const s16x4*)&plds[w][par][16 + r][8 * g];
            s16x4 h1 = *(const s16x4*)&plds[w][par][16 + r][8 * g + 4];
            s16x8 pb0 = {l0[0], l0[1], l0[2], l0[3], h0[0], h0[1], h0[2], h0[3]};
            s16x8 pb1 = {l1[0], l1[1], l1[2], l1[3], h1[0], h1[1], h1[2], h1[3]};

            acc00 = __builtin_amdgcn_mfma_f32_16x16x32_bf16(ka0, pb0, acc00, 0, 0, 0);
            acc10 = __builtin_amdgcn_mfma_f32_16x16x32_bf16(ka1, pb0, acc10, 0, 0, 0);
            acc01 = __builtin_amdgcn_mfma_f32_16x16x32_bf16(ka0, pb1, acc01, 0, 0, 0);
            acc11 = __builtin_amdgcn_mfma_f32_16x16x32_bf16(ka1, pb1, acc11, 0, 0, 0);
        }
    }

    short* dst = avp + ((size_t)blockIdx.z * NBATCH + b) * NPIX * CI;
    u32x2 o00 = {cvtpk(acc00[0], acc00[1]), cvtpk(acc00[2], acc00[3])};
    u32x2 o10 = {cvtpk(acc10[0], acc10[1]), cvtpk(acc10[2], acc10[3])};
    u32x2 o01 = {cvtpk(acc01[0], acc01[1]), cvtpk(acc01[2], acc01[3])};
    u32x2 o11 = {cvtpk(acc11[0], acc11[1]), cvtpk(acc11[2], acc11[3])};
    *(u32x2*)(dst + (size_t)(m0 + r) * CI + 4 * g)           = o00;
    *(u32x2*)(dst + (size_t)(m0 + r) * CI + 16 + 4 * g)      = o10;
    *(u32x2*)(dst + (size_t)(m0 + 16 + r) * CI + 4 * g)      = o01;
    *(u32x2*)(dst + (size_t)(m0 + 16 + r) * CI + 16 + 4 * g) = o11;
}

// ---------------------------------------------------------------------------
// E0: av[b][m][c] (bf16) = sum_z avp[z][b][m][c]; one u32 (2 ch) per thread
// ---------------------------------------------------------------------------
__global__ __launch_bounds__(256) void e_red(
    const short* __restrict__ avp, short* __restrict__ av, int nsa)
{
    int idx = blockIdx.x * 256 + threadIdx.x;   // over NBATCH*NPIX*CI/2 u32s
    const unsigned* src = (const unsigned*)avp;
    float lo = 0.f, hi = 0.f;
    for (int zz = 0; zz < nsa; zz++) {
        unsigned p = src[(size_t)zz * (NBATCH * NPIX * CI / 2) + idx];
        lo += b2f((short)(p & 0xFFFF));
        hi += b2f((short)(p >> 16));
    }
    ((unsigned*)av)[idx] = cvtpk(lo, hi);
}

// ---------------------------------------------------------------------------
// E1: out = relu( BN2( Wo @ BN1(Wg @ av) + bo ) + xB ), 16 ch per y-block
// ---------------------------------------------------------------------------
__global__ __launch_bounds__(256) void e_fused(
    const short* __restrict__ av,
    const float* __restrict__ Wg,
    const float* __restrict__ g1g, const float* __restrict__ g1b,
    const float* __restrict__ g1m, const float* __restrict__ g1v,
    const float* __restrict__ Wo, const float* __restrict__ bo,
    const float* __restrict__ g2g, const float* __restrict__ g2b,
    const float* __restrict__ g2m, const float* __restrict__ g2v,
    const float* __restrict__ xB, float* __restrict__ out)
{
    __shared__ float sWg[CI * CI], sWo[16 * CI], s1[CI], t1[CI], s2[16], t2[16];
    int t = threadIdx.x, jq = blockIdx.y;   // jq: 0..3, 16 channels each
    for (int i = t; i < CI * CI; i += 256) sWg[i] = Wg[i];
    for (int i = t; i < 16 * CI; i += 256) sWo[i] = Wo[jq * 16 * CI + i];
    if (t < CI) {
        float s = g1g[t] * rsqrtf(g1v[t] + 1e-5f);
        s1[t] = s; t1[t] = g1b[t] - g1m[t] * s;
    } else if (t < CI + 16) {
        int j = jq * 16 + (t - CI);
        float s = g2g[j] * rsqrtf(g2v[j] + 1e-5f);
        s2[t - CI] = s; t2[t - CI] = g2b[j] - g2m[j] * s + bo[j] * s;
    }
    __syncthreads();

    int idx = blockIdx.x * 256 + t;   // b*NPIX + m
    int b = idx / NPIX, m = idx % NPIX;

    float a[CI];
    const short* p = av + (size_t)idx * CI;
    #pragma unroll
    for (int v8 = 0; v8 < 4; v8++) {
        s16x8 tv = *(const s16x8*)(p + 8 * v8);
        #pragma unroll
        for (int j = 0; j < 8; j++) a[8 * v8 + j] = b2f(tv[j]);
    }
    float a2[CI];
    #pragma unroll
    for (int o = 0; o < CI; o++) {
        float acc = 0.f;
        #pragma unroll
        for (int c = 0; c < CI; c++) acc += sWg[o * CI + c] * a[c];
        a2[o] = acc * s1[o] + t1[o];
    }
    #pragma unroll
    for (int jj = 0; jj < 16; jj++) {
        float acc = 0.f;
        #pragma unroll
        for (int o = 0; o < CI; o++) acc += sWo[jj * CI + o] * a2[o];
        acc = acc * s2[jj] + t2[jj];
        size_t oi = ((size_t)b * CC + jq * 16 + jj) * NPIX + m;
        float res = acc + xB[oi];
        out[oi] = res > 0.f ? res : 0.f;
    }
}

// ---------------------------------------------------------------------------
extern "C" void kernel_launch(void* const* d_in, const int* in_sizes, int n_in,
                              void* d_out, int out_size, void* d_ws, size_t ws_size,
                              hipStream_t stream)
{
    const float* xA = (const float*)d_in[0];
    const float* xB = (const float*)d_in[1];
    const float* Wk = (const float*)d_in[2];
    const float* bk = (const float*)d_in[3];
    const float* Wv = (const float*)d_in[4];
    const float* bv = (const float*)d_in[5];
    const float* Wq = (const float*)d_in[6];
    const float* bq = (const float*)d_in[7];
    const float* Wg = (const float*)d_in[8];
    const float* g1g = (const float*)d_in[9];
    const float* g1b = (const float*)d_in[10];
    const float* g1m = (const float*)d_in[11];
    const float* g1v = (const float*)d_in[12];
    const float* Wo = (const float*)d_in[13];
    const float* bo = (const float*)d_in[14];
    const float* g2g = (const float*)d_in[15];
    const float* g2b = (const float*)d_in[16];
    const float* g2m = (const float*)d_in[17];
    const float* g2v = (const float*)d_in[18];
    float* out = (float*)d_out;

    char* ws = (char*)d_ws;
    const size_t SZB = (size_t)NBATCH * NPIX * CI * 2;       // 1,179,648 B
    short* vT = (short*)(ws);                                 // dead after k_attn
    short* qT = (short*)(ws + SZB);
    short* kC = (short*)(ws + 2 * SZB);
    float* invd = (float*)(ws + 3 * SZB);                     // NBATCH*NPIX f32
    char*  region = ws + 3 * SZB + (size_t)NBATCH * NPIX * 4;
    float* sum_part = (float*)region;                         // dead after k_invd
    short* avp = (short*)region;                              // overlays sum_part
    short* av = vT;                                           // overlays vT

    // pick attention n-split by available workspace
    const size_t base = 3 * SZB + (size_t)NBATCH * NPIX * 4;
    int nsa = (ws_size >= base + (size_t)16 * NBATCH * NPIX * CI * 2) ? 16 : 8;
    int slice = NPIX / nsa;   // 576 or 1152, both multiples of 64

    k_proj<<<dim3(NBATCH * NPIX / 64, 3), dim3(256), 0, stream>>>(
        xA, xB, Wk, bk, Wv, bv, Wq, bq, vT, qT, kC);
    k_denom<<<dim3(NPIX / 64, NBATCH, NSD), dim3(128), 0, stream>>>(
        vT, qT, sum_part);
    k_invd<<<dim3(NBATCH * NPIX / 256), dim3(256), 0, stream>>>(
        sum_part, invd);
    k_scale<<<dim3(NBATCH * CI * NPIX / 256), dim3(256), 0, stream>>>(
        kC, invd);
    k_attn<<<dim3(NPIX / 64, NBATCH, nsa), dim3(128), 0, stream>>>(
        vT, qT, kC, avp, slice);
    e_red<<<dim3(NBATCH * NPIX * CI / 2 / 256), dim3(256), 0, stream>>>(
        avp, av, nsa);
    e_fused<<<dim3(NBATCH * NPIX / 256, 4), dim3(256), 0, stream>>>(
        av, Wg, g1g, g1b, g1m, g1v, Wo, bo, g2g, g2b, g2m, g2v, xB, out);
}

// Round 8
// 127.031 us; speedup vs baseline: 2.1822x; 1.0507x over previous
//
#include <hip/hip_runtime.h>
#include <hip/hip_bf16.h>

#define CI 32
#define CC 64
#define NBATCH 2
#define NPIX 9216          // 96*96
#define NSD 24             // m-splits for k_denom (NPIX/24 = 384)
#define LOG2E 1.4426950408889634f

typedef __attribute__((ext_vector_type(8))) short s16x8;
typedef __attribute__((ext_vector_type(4))) short s16x4;
typedef __attribute__((ext_vector_type(4))) float f32x4;
typedef __attribute__((ext_vector_type(2))) unsigned int u32x2;
typedef __attribute__((ext_vector_type(4))) unsigned int u32x4;

static __device__ __forceinline__ unsigned cvtpk(float a, float b) {
    unsigned d;
    asm("v_cvt_pk_bf16_f32 %0, %1, %2" : "=v"(d) : "v"(a), "v"(b));
    return d;
}
static __device__ __forceinline__ short f2b(float f) {
    union { float f; unsigned u; } v; v.f = f;
    return (short)((v.u + 0x7FFFu + ((v.u >> 16) & 1u)) >> 16);
}
static __device__ __forceinline__ float b2f(short s) {
    union { unsigned u; float f; } v; v.u = ((unsigned)(unsigned short)s) << 16;
    return v.f;
}
static __device__ __forceinline__ s16x8 asS16x8(u32x4 v) {
    union { u32x4 u; s16x8 s; } c; c.u = v; return c.s;
}

// ---------------------------------------------------------------------------
// K0: 1x1 conv projections. grid (NBATCH*NPIX/64, 3). 256 thr: 4-way c-split
//  mode 0: kC[b][c][n]   mode 1: vT[b][n][c]   mode 2: qT[b][n][c] * log2(e)
// ---------------------------------------------------------------------------
__global__ __launch_bounds__(256) void k_proj(
    const float* __restrict__ xA, const float* __restrict__ xB,
    const float* __restrict__ Wk, const float* __restrict__ bk,
    const float* __restrict__ Wv, const float* __restrict__ bv,
    const float* __restrict__ Wq, const float* __restrict__ bq,
    short* __restrict__ vT, short* __restrict__ qT, short* __restrict__ kC)
{
    int mode = blockIdx.y;
    const float* W    = mode == 0 ? Wk : (mode == 1 ? Wv : Wq);
    const float* bias = mode == 0 ? bk : (mode == 1 ? bv : bq);
    const float* X    = mode == 2 ? xB : xA;

    __shared__ float sW[CI * CC];
    __shared__ float sb[CI];
    __shared__ float spart[3][64][33];
    for (int i = threadIdx.x; i < CI * CC; i += 256) sW[i] = W[i];
    if (threadIdx.x < CI) sb[threadIdx.x] = bias[threadIdx.x];
    __syncthreads();

    int q4 = threadIdx.x >> 6;      // c-quarter
    int lp = threadIdx.x & 63;      // local pixel
    int idx = blockIdx.x * 64 + lp; // 0 .. NBATCH*NPIX-1
    int b = idx / NPIX, n = idx % NPIX;

    float acc[CI];
    #pragma unroll
    for (int o = 0; o < CI; o++) acc[o] = 0.f;

    const float* px = X + (size_t)b * CC * NPIX + n;
    #pragma unroll
    for (int cc = 0; cc < 16; cc++) {
        int c = q4 * 16 + cc;
        float x = px[(size_t)c * NPIX];
        #pragma unroll
        for (int o = 0; o < CI; o++) acc[o] += sW[o * CC + c] * x;
    }
    if (q4) {
        #pragma unroll
        for (int o = 0; o < CI; o++) spart[q4 - 1][lp][o] = acc[o];
    }
    __syncthreads();
    if (q4 == 0) {
        #pragma unroll
        for (int o = 0; o < CI; o++)
            acc[o] += spart[0][lp][o] + spart[1][lp][o] + spart[2][lp][o] + sb[o];
        if (mode == 0) {
            #pragma unroll
            for (int o = 0; o < CI; o++)
                kC[((size_t)b * CI + o) * NPIX + n] = f2b(acc[o]);
        } else {
            float sc = (mode == 2) ? LOG2E : 1.0f;
            short* dst = (mode == 1 ? vT : qT) + ((size_t)b * NPIX + n) * CI;
            #pragma unroll
            for (int v4 = 0; v4 < 4; v4++) {
                u32x4 pk;
                #pragma unroll
                for (int j = 0; j < 4; j++)
                    pk[j] = cvtpk(acc[v4 * 8 + 2 * j] * sc, acc[v4 * 8 + 2 * j + 1] * sc);
                ((u32x4*)dst)[v4] = pk;
            }
        }
    }
}

// ---------------------------------------------------------------------------
// K1: sum_part[z][b][n] = sum over m-slice of exp2(S'[n,m]).
// 64-thr blocks, prefetched q fragments.
// ---------------------------------------------------------------------------
__global__ __launch_bounds__(64) void k_denom(
    const short* __restrict__ vT, const short* __restrict__ qT,
    float* __restrict__ sum_part)
{
    int lane = threadIdx.x;
    int r = lane & 15, g = lane >> 4;
    int b = blockIdx.y;
    int nb = blockIdx.x * 32;

    const short* vb = vT + (size_t)b * NPIX * CI;
    s16x8 a0 = *(const s16x8*)(vb + (size_t)(nb + r) * CI + 8 * g);
    s16x8 a1 = *(const s16x8*)(vb + (size_t)(nb + 16 + r) * CI + 8 * g);

    f32x4 s0 = {0.f, 0.f, 0.f, 0.f}, s1 = {0.f, 0.f, 0.f, 0.f};
    f32x4 z  = {0.f, 0.f, 0.f, 0.f};
    const short* qb = qT + (size_t)b * NPIX * CI;
    int mlo = blockIdx.z * (NPIX / NSD);
    int mhi = mlo + NPIX / NSD;

    s16x8 q0 = *(const s16x8*)(qb + (size_t)(mlo + r) * CI + 8 * g);
    s16x8 q1 = *(const s16x8*)(qb + (size_t)(mlo + 16 + r) * CI + 8 * g);
    for (int m0 = mlo; m0 < mhi; m0 += 32) {
        int np = (m0 + 32 < mhi) ? m0 + 32 : mlo;
        s16x8 nq0 = *(const s16x8*)(qb + (size_t)(np + r) * CI + 8 * g);
        s16x8 nq1 = *(const s16x8*)(qb + (size_t)(np + 16 + r) * CI + 8 * g);

        f32x4 t00 = __builtin_amdgcn_mfma_f32_16x16x32_bf16(a0, q0, z, 0, 0, 0);
        f32x4 t01 = __builtin_amdgcn_mfma_f32_16x16x32_bf16(a0, q1, z, 0, 0, 0);
        f32x4 t10 = __builtin_amdgcn_mfma_f32_16x16x32_bf16(a1, q0, z, 0, 0, 0);
        f32x4 t11 = __builtin_amdgcn_mfma_f32_16x16x32_bf16(a1, q1, z, 0, 0, 0);
        #pragma unroll
        for (int e = 0; e < 4; e++) {
            s0[e] += __builtin_amdgcn_exp2f(t00[e]) + __builtin_amdgcn_exp2f(t01[e]);
            s1[e] += __builtin_amdgcn_exp2f(t10[e]) + __builtin_amdgcn_exp2f(t11[e]);
        }
        q0 = nq0; q1 = nq1;
    }
    #pragma unroll
    for (int mask = 1; mask < 16; mask <<= 1) {
        #pragma unroll
        for (int e = 0; e < 4; e++) {
            s0[e] += __shfl_xor(s0[e], mask, 64);
            s1[e] += __shfl_xor(s1[e], mask, 64);
        }
    }
    if (r == 0) {
        float* sp = sum_part + ((size_t)blockIdx.z * NBATCH + b) * NPIX;
        #pragma unroll
        for (int e = 0; e < 4; e++) {
            sp[nb + 4 * g + e]      = s0[e];
            sp[nb + 16 + 4 * g + e] = s1[e];
        }
    }
}

// ---------------------------------------------------------------------------
// K1b: invd[b][n] = 1 / sum_z sum_part[z][b][n]
// ---------------------------------------------------------------------------
__global__ __launch_bounds__(256) void k_invd(
    const float* __restrict__ sum_part, float* __restrict__ invd)
{
    int idx = blockIdx.x * 256 + threadIdx.x;   // b*NPIX + n
    float s = 0.f;
    #pragma unroll
    for (int zz = 0; zz < NSD; zz++)
        s += sum_part[(size_t)zz * NBATCH * NPIX + idx];
    invd[idx] = 1.0f / s;
}

// ---------------------------------------------------------------------------
// K1c: kC[b][c][n] *= invd[b][n]
// ---------------------------------------------------------------------------
__global__ __launch_bounds__(256) void k_scale(
    short* __restrict__ kC, const float* __restrict__ invd)
{
    int idx = blockIdx.x * 256 + threadIdx.x;   // (b*CI+c)*NPIX + n
    int n = idx % NPIX;
    int b = idx / (CI * NPIX);
    kC[idx] = f2b(b2f(kC[idx]) * invd[b * NPIX + n]);
}

// ---------------------------------------------------------------------------
// K2: avp[z][b][m][c] (bf16) = sum over n-slice of k'[c,n] * exp2(S'[n,m])
// 64-thr blocks (1 wave, 32 m-cols), explicit next-iter global prefetch.
// ---------------------------------------------------------------------------
__global__ __launch_bounds__(64) void k_attn(
    const short* __restrict__ vT, const short* __restrict__ qT,
    const short* __restrict__ kC, short* __restrict__ avp, int slice)
{
    __shared__ short plds[32][36];  // [m-local][n-local], stride 36
    int lane = threadIdx.x;
    int r = lane & 15, g = lane >> 4;
    int b = blockIdx.y;
    int m0 = blockIdx.x * 32;

    const short* qb = qT + (size_t)b * NPIX * CI;
    s16x8 qb0 = *(const s16x8*)(qb + (size_t)(m0 + r) * CI + 8 * g);
    s16x8 qb1 = *(const s16x8*)(qb + (size_t)(m0 + 16 + r) * CI + 8 * g);

    const short* vb = vT + (size_t)b * NPIX * CI;
    const short* k0 = kC + ((size_t)b * CI + r) * NPIX;
    const short* k1 = k0 + (size_t)16 * NPIX;

    f32x4 acc00 = {0,0,0,0}, acc01 = {0,0,0,0}, acc10 = {0,0,0,0}, acc11 = {0,0,0,0};
    f32x4 z = {0,0,0,0};

    int nlo = blockIdx.z * slice;
    int nhi = nlo + slice;

    s16x8 a0  = *(const s16x8*)(vb + (size_t)(nlo + r) * CI + 8 * g);
    s16x8 a1  = *(const s16x8*)(vb + (size_t)(nlo + 16 + r) * CI + 8 * g);
    s16x8 ka0 = *(const s16x8*)(k0 + nlo + 8 * g);
    s16x8 ka1 = *(const s16x8*)(k1 + nlo + 8 * g);

    for (int n0 = nlo; n0 < nhi; n0 += 32) {
        int np = (n0 + 32 < nhi) ? n0 + 32 : nlo;
        s16x8 na0  = *(const s16x8*)(vb + (size_t)(np + r) * CI + 8 * g);
        s16x8 na1  = *(const s16x8*)(vb + (size_t)(np + 16 + r) * CI + 8 * g);
        s16x8 nka0 = *(const s16x8*)(k0 + np + 8 * g);
        s16x8 nka1 = *(const s16x8*)(k1 + np + 8 * g);

        f32x4 t00 = __builtin_amdgcn_mfma_f32_16x16x32_bf16(a0, qb0, z, 0, 0, 0);
        f32x4 t01 = __builtin_amdgcn_mfma_f32_16x16x32_bf16(a0, qb1, z, 0, 0, 0);
        f32x4 t10 = __builtin_amdgcn_mfma_f32_16x16x32_bf16(a1, qb0, z, 0, 0, 0);
        f32x4 t11 = __builtin_amdgcn_mfma_f32_16x16x32_bf16(a1, qb1, z, 0, 0, 0);

        u32x2 w00 = {cvtpk(__builtin_amdgcn_exp2f(t00[0]), __builtin_amdgcn_exp2f(t00[1])),
                     cvtpk(__builtin_amdgcn_exp2f(t00[2]), __builtin_amdgcn_exp2f(t00[3]))};
        u32x2 w10 = {cvtpk(__builtin_amdgcn_exp2f(t10[0]), __builtin_amdgcn_exp2f(t10[1])),
                     cvtpk(__builtin_amdgcn_exp2f(t10[2]), __builtin_amdgcn_exp2f(t10[3]))};
        u32x2 w01 = {cvtpk(__builtin_amdgcn_exp2f(t01[0]), __builtin_amdgcn_exp2f(t01[1])),
                     cvtpk(__builtin_amdgcn_exp2f(t01[2]), __builtin_amdgcn_exp2f(t01[3]))};
        u32x2 w11 = {cvtpk(__builtin_amdgcn_exp2f(t11[0]), __builtin_amdgcn_exp2f(t11[1])),
                     cvtpk(__builtin_amdgcn_exp2f(t11[2]), __builtin_amdgcn_exp2f(t11[3]))};

        // P tile [m-local][n-local]
        *(u32x2*)&plds[r][4 * g]           = w00;
        *(u32x2*)&plds[r][16 + 4 * g]      = w10;
        *(u32x2*)&plds[16 + r][4 * g]      = w01;
        *(u32x2*)&plds[16 + r][16 + 4 * g] = w11;

        s16x4 l0 = *(const s16x4*)&plds[r][8 * g];
        s16x4 h0 = *(const s16x4*)&plds[r][8 * g + 4];
        s16x4 l1 = *(const s16x4*)&plds[16 + r][8 * g];
        s16x4 h1 = *(const s16x4*)&plds[16 + r][8 * g + 4];
        s16x8 pb0 = {l0[0], l0[1], l0[2], l0[3], h0[0], h0[1], h0[2], h0[3]};
        s16x8 pb1 = {l1[0], l1[1], l1[2], l1[3], h1[0], h1[1], h1[2], h1[3]};

        acc00 = __builtin_amdgcn_mfma_f32_16x16x32_bf16(ka0, pb0, acc00, 0, 0, 0);
        acc10 = __builtin_amdgcn_mfma_f32_16x16x32_bf16(ka1, pb0, acc10, 0, 0, 0);
        acc01 = __builtin_amdgcn_mfma_f32_16x16x32_bf16(ka0, pb1, acc01, 0, 0, 0);
        acc11 = __builtin_amdgcn_mfma_f32_16x16x32_bf16(ka1, pb1, acc11, 0, 0, 0);

        a0 = na0; a1 = na1; ka0 = nka0; ka1 = nka1;
    }

    short* dst = avp + ((size_t)blockIdx.z * NBATCH + b) * NPIX * CI;
    u32x2 o00 = {cvtpk(acc00[0], acc00[1]), cvtpk(acc00[2], acc00[3])};
    u32x2 o10 = {cvtpk(acc10[0], acc10[1]), cvtpk(acc10[2], acc10[3])};
    u32x2 o01 = {cvtpk(acc01[0], acc01[1]), cvtpk(acc01[2], acc01[3])};
    u32x2 o11 = {cvtpk(acc11[0], acc11[1]), cvtpk(acc11[2], acc11[3])};
    *(u32x2*)(dst + (size_t)(m0 + r) * CI + 4 * g)           = o00;
    *(u32x2*)(dst + (size_t)(m0 + r) * CI + 16 + 4 * g)      = o10;
    *(u32x2*)(dst + (size_t)(m0 + 16 + r) * CI + 4 * g)      = o01;
    *(u32x2*)(dst + (size_t)(m0 + 16 + r) * CI + 16 + 4 * g) = o11;
}

// ---------------------------------------------------------------------------
// E0: av[b][m][c] (bf16) = sum_z avp[z][b][m][c]; one u32 (2 ch) per thread
// ---------------------------------------------------------------------------
__global__ __launch_bounds__(256) void e_red(
    const short* __restrict__ avp, short* __restrict__ av, int nsa)
{
    int idx = blockIdx.x * 256 + threadIdx.x;   // over NBATCH*NPIX*CI/2 u32s
    const unsigned* src = (const unsigned*)avp;
    float lo = 0.f, hi = 0.f;
    for (int zz = 0; zz < nsa; zz++) {
        unsigned p = src[(size_t)zz * (NBATCH * NPIX * CI / 2) + idx];
        lo += b2f((short)(p & 0xFFFF));
        hi += b2f((short)(p >> 16));
    }
    ((unsigned*)av)[idx] = cvtpk(lo, hi);
}

// ---------------------------------------------------------------------------
// E1 (MFMA): out = relu( BN2( Wo @ BN1(Wg @ av) + bo ) + xB )
// 256 thr = 4 waves; each wave handles 16 pixels (MFMA j-dim), 6 MFMAs.
// BN scales folded into weight rows (bf16); offsets added in f32.
// ---------------------------------------------------------------------------
__global__ __launch_bounds__(256) void e_fused(
    const short* __restrict__ av,
    const float* __restrict__ Wg,
    const float* __restrict__ g1g, const float* __restrict__ g1b,
    const float* __restrict__ g1m, const float* __restrict__ g1v,
    const float* __restrict__ Wo, const float* __restrict__ bo,
    const float* __restrict__ g2g, const float* __restrict__ g2b,
    const float* __restrict__ g2m, const float* __restrict__ g2v,
    const float* __restrict__ xB, float* __restrict__ out)
{
    __shared__ float s1s[CI], t1s[CI], s2s[CC], t2s[CC];
    __shared__ short sa2[4][16][36];
    int t = threadIdx.x;
    if (t < CC) {
        float s = g2g[t] * rsqrtf(g2v[t] + 1e-5f);
        s2s[t] = s; t2s[t] = g2b[t] - g2m[t] * s + bo[t] * s;
    } else if (t < CC + CI) {
        int o = t - CC;
        float s = g1g[o] * rsqrtf(g1v[o] + 1e-5f);
        s1s[o] = s; t1s[o] = g1b[o] - g1m[o] * s;
    }
    __syncthreads();

    int w = t >> 6, lane = t & 63;
    int r = lane & 15, g = lane >> 4;
    int idx0 = blockIdx.x * 64 + w * 16;        // flat pixel base (b*NPIX+m)
    int b = idx0 / NPIX;
    int mcol = (idx0 % NPIX) + r;

    // A1 frags: Wg rows r and 16+r, cols 8g..8g+7, scaled by s1
    const float* wg0 = Wg + r * CI + 8 * g;
    const float* wg1 = Wg + (16 + r) * CI + 8 * g;
    float sA = s1s[r], sB = s1s[16 + r];
    u32x4 a1l, a1h;
    #pragma unroll
    for (int j = 0; j < 4; j++) {
        a1l[j] = cvtpk(wg0[2 * j] * sA, wg0[2 * j + 1] * sA);
        a1h[j] = cvtpk(wg1[2 * j] * sB, wg1[2 * j + 1] * sB);
    }
    s16x8 A1lo = asS16x8(a1l), A1hi = asS16x8(a1h);

    // B frag: av rows (16 pixels idx0..idx0+15), channels 8g..8g+7
    s16x8 Bav = *(const s16x8*)(av + (size_t)(idx0 + r) * CI + 8 * g);

    f32x4 z = {0, 0, 0, 0};
    f32x4 d1lo = __builtin_amdgcn_mfma_f32_16x16x32_bf16(A1lo, Bav, z, 0, 0, 0);
    f32x4 d1hi = __builtin_amdgcn_mfma_f32_16x16x32_bf16(A1hi, Bav, z, 0, 0, 0);

    // a2[o][pixel] = d1 + t1[o]; pack to LDS tile [pixel][o]
    u32x2 plo = {cvtpk(d1lo[0] + t1s[4 * g],     d1lo[1] + t1s[4 * g + 1]),
                 cvtpk(d1lo[2] + t1s[4 * g + 2], d1lo[3] + t1s[4 * g + 3])};
    u32x2 phi = {cvtpk(d1hi[0] + t1s[16 + 4 * g],     d1hi[1] + t1s[16 + 4 * g + 1]),
                 cvtpk(d1hi[2] + t1s[16 + 4 * g + 2], d1hi[3] + t1s[16 + 4 * g + 3])};
    *(u32x2*)&sa2[w][r][4 * g]      = plo;
    *(u32x2*)&sa2[w][r][16 + 4 * g] = phi;

    s16x4 l0 = *(const s16x4*)&sa2[w][r][8 * g];
    s16x4 h0 = *(const s16x4*)&sa2[w][r][8 * g + 4];
    s16x8 B2 = {l0[0], l0[1], l0[2], l0[3], h0[0], h0[1], h0[2], h0[3]};

    // 4 output-row tiles of Wo' (16 rows each), K=32
    #pragma unroll
    for (int h = 0; h < 4; h++) {
        const float* wo = Wo + (size_t)(16 * h + r) * CI + 8 * g;
        float s = s2s[16 * h + r];
        u32x4 aw;
        #pragma unroll
        for (int j = 0; j < 4; j++)
            aw[j] = cvtpk(wo[2 * j] * s, wo[2 * j + 1] * s);
        f32x4 d2 = __builtin_amdgcn_mfma_f32_16x16x32_bf16(asS16x8(aw), B2, z, 0, 0, 0);
        #pragma unroll
        for (int e = 0; e < 4; e++) {
            int ch = 16 * h + 4 * g + e;
            size_t oi = ((size_t)b * CC + ch) * NPIX + mcol;
            float v = d2[e] + t2s[ch] + xB[oi];
            out[oi] = v > 0.f ? v : 0.f;
        }
    }
}

// ---------------------------------------------------------------------------
extern "C" void kernel_launch(void* const* d_in, const int* in_sizes, int n_in,
                              void* d_out, int out_size, void* d_ws, size_t ws_size,
                              hipStream_t stream)
{
    const float* xA = (const float*)d_in[0];
    const float* xB = (const float*)d_in[1];
    const float* Wk = (const float*)d_in[2];
    const float* bk = (const float*)d_in[3];
    const float* Wv = (const float*)d_in[4];
    const float* bv = (const float*)d_in[5];
    const float* Wq = (const float*)d_in[6];
    const float* bq = (const float*)d_in[7];
    const float* Wg = (const float*)d_in[8];
    const float* g1g = (const float*)d_in[9];
    const float* g1b = (const float*)d_in[10];
    const float* g1m = (const float*)d_in[11];
    const float* g1v = (const float*)d_in[12];
    const float* Wo = (const float*)d_in[13];
    const float* bo = (const float*)d_in[14];
    const float* g2g = (const float*)d_in[15];
    const float* g2b = (const float*)d_in[16];
    const float* g2m = (const float*)d_in[17];
    const float* g2v = (const float*)d_in[18];
    float* out = (float*)d_out;

    char* ws = (char*)d_ws;
    const size_t SZB = (size_t)NBATCH * NPIX * CI * 2;       // 1,179,648 B
    short* vT = (short*)(ws);                                 // dead after k_attn
    short* qT = (short*)(ws + SZB);
    short* kC = (short*)(ws + 2 * SZB);
    float* invd = (float*)(ws + 3 * SZB);                     // NBATCH*NPIX f32
    char*  region = ws + 3 * SZB + (size_t)NBATCH * NPIX * 4;
    float* sum_part = (float*)region;                         // dead after k_invd
    short* avp = (short*)region;                              // overlays sum_part
    short* av = vT;                                           // overlays vT

    // pick attention n-split by available workspace
    const size_t base = 3 * SZB + (size_t)NBATCH * NPIX * 4;
    int nsa = (ws_size >= base + (size_t)16 * NBATCH * NPIX * CI * 2) ? 16 : 8;
    int slice = NPIX / nsa;   // 576 or 1152

    k_proj<<<dim3(NBATCH * NPIX / 64, 3), dim3(256), 0, stream>>>(
        xA, xB, Wk, bk, Wv, bv, Wq, bq, vT, qT, kC);
    k_denom<<<dim3(NPIX / 32, NBATCH, NSD), dim3(64), 0, stream>>>(
        vT, qT, sum_part);
    k_invd<<<dim3(NBATCH * NPIX / 256), dim3(256), 0, stream>>>(
        sum_part, invd);
    k_scale<<<dim3(NBATCH * CI * NPIX / 256), dim3(256), 0, stream>>>(
        kC, invd);
    k_attn<<<dim3(NPIX / 32, NBATCH, nsa), dim3(64), 0, stream>>>(
        vT, qT, kC, avp, slice);
    e_red<<<dim3(NBATCH * NPIX * CI / 2 / 256), dim3(256), 0, stream>>>(
        avp, av, nsa);
    e_fused<<<dim3(NBATCH * NPIX / 64), dim3(256), 0, stream>>>(
        av, Wg, g1g, g1b, g1m, g1v, Wo, bo, g2g, g2b, g2m, g2v, xB, out);
}